// Round 14
// baseline (364.576 us; speedup 1.0000x reference)
//
#include <hip/hip_runtime.h>
#include <hip/hip_bf16.h>

using bf16 = __hip_bfloat16;
typedef short bf16x8 __attribute__((ext_vector_type(8)));
typedef float f32x4 __attribute__((ext_vector_type(4)));

#define CB 2
#define CS 2048
#define CD 1024
#define CH 16
#define CKH 4
#define CHD 64
#define CREP 4
#define CNQ (CH*CHD)    // 1024
#define CNKV (CKH*CHD)  // 256
#define CM (CB*CS)      // 4096

__device__ __forceinline__ unsigned short f2bf(float f) {
  union { float f; unsigned int i; } c; c.f = f;
  unsigned int r = c.i + 0x7FFFu + ((c.i >> 16) & 1u);  // RNE
  return (unsigned short)(r >> 16);
}
__device__ __forceinline__ float bf2f(unsigned short u) {
  union { unsigned int i; float f; } c;
  c.i = ((unsigned int)u) << 16;
  return c.f;
}
__device__ __forceinline__ void gload_lds16(const void* g, void* l) {
  __builtin_amdgcn_global_load_lds(
      (const __attribute__((address_space(1))) void*)g,
      (__attribute__((address_space(3))) void*)l, 16, 0, 0);
}

// ---------------------------------------------------------------------------
// bf16 MFMA GEMM v2 (R8-proven): C[M,N] f32 = A[M,K](lda) · Bt[N,K]^T.
// ---------------------------------------------------------------------------
__global__ __launch_bounds__(256) void gemm_mfma_kernel(
    const bf16* __restrict__ A, const bf16* __restrict__ Bt,
    float* __restrict__ C, int Mm, int Nn, int Kk, int lda)
{
  __shared__ __align__(16) bf16 As[2][128 * 32];
  __shared__ __align__(16) bf16 Bs[2][128 * 32];
  const int tid = threadIdx.x;
  const int lane = tid & 63;
  const int l15 = lane & 15;
  const int g = lane >> 4;
  const int wid = tid >> 6;
  const int wr = (wid >> 1) * 64;
  const int wc = (wid & 1) * 64;
  const int m0 = blockIdx.x * 128;
  const int n0 = blockIdx.y * 128;

  f32x4 acc[4][4];
  #pragma unroll
  for (int i = 0; i < 4; ++i)
    #pragma unroll
    for (int j = 0; j < 4; ++j)
      acc[i][j] = (f32x4){0.f, 0.f, 0.f, 0.f};

  const int sr = tid >> 2;
  const int sc = (tid & 3) * 8;
  const bf16* aSrc = A + (size_t)(m0 + sr) * lda + sc;
  const bf16* bSrc = Bt + (size_t)(n0 + sr) * Kk + sc;
  const int sOff = (tid & 192) * 8;

#define GSTAGE(bi, k0) do {                                             \
    gload_lds16(aSrc + (k0),                     &As[bi][sOff]);        \
    gload_lds16(aSrc + 64 * (size_t)lda + (k0),  &As[bi][sOff + 2048]); \
    gload_lds16(bSrc + (k0),                     &Bs[bi][sOff]);        \
    gload_lds16(bSrc + 64 * (size_t)Kk + (k0),   &Bs[bi][sOff + 2048]); \
  } while (0)

  const int nt = Kk >> 5;
  int bi = 0;
  GSTAGE(0, 0);
  for (int t = 0; t < nt; ++t) {
    if (t + 1 < nt) {
      GSTAGE(bi ^ 1, (t + 1) * 32);
      asm volatile("s_waitcnt vmcnt(4)" ::: "memory");
    } else {
      asm volatile("s_waitcnt vmcnt(0)" ::: "memory");
    }
    __builtin_amdgcn_s_barrier();
    asm volatile("" ::: "memory");

    bf16x8 af[4], bfr[4];
    #pragma unroll
    for (int mt = 0; mt < 4; ++mt)
      af[mt] = *(const bf16x8*)&As[bi][(wr + mt * 16 + l15) * 32 + g * 8];
    #pragma unroll
    for (int nt2 = 0; nt2 < 4; ++nt2)
      bfr[nt2] = *(const bf16x8*)&Bs[bi][(wc + nt2 * 16 + l15) * 32 + g * 8];
    #pragma unroll
    for (int mt = 0; mt < 4; ++mt)
      #pragma unroll
      for (int nt2 = 0; nt2 < 4; ++nt2)
        acc[mt][nt2] = __builtin_amdgcn_mfma_f32_16x16x32_bf16(af[mt], bfr[nt2], acc[mt][nt2], 0, 0, 0);

    asm volatile("" ::: "memory");
    __builtin_amdgcn_s_barrier();
    bi ^= 1;
  }
#undef GSTAGE

  #pragma unroll
  for (int mt = 0; mt < 4; ++mt)
    #pragma unroll
    for (int r4 = 0; r4 < 4; ++r4) {
      const size_t row = (size_t)(m0 + wr + mt * 16 + 4 * g + r4);
      #pragma unroll
      for (int nt2 = 0; nt2 < 4; ++nt2)
        C[row * Nn + n0 + wc + nt2 * 16 + l15] = acc[mt][nt2][r4];
    }
}

// ---------------------------------------------------------------------------
// qkv GEMM with fused RoPE + layout epilogue (R12-proven).
// ---------------------------------------------------------------------------
__global__ __launch_bounds__(256) void gemm_qkv_rope_kernel(
    const bf16* __restrict__ A, const bf16* __restrict__ Bt,
    const float* __restrict__ fc, const float* __restrict__ fs,
    bf16* __restrict__ qb, bf16* __restrict__ kb, bf16* __restrict__ vt)
{
  __shared__ __align__(16) bf16 As[2][128 * 32];
  __shared__ __align__(16) bf16 Bs[2][128 * 32];
  const int tid = threadIdx.x;
  const int lane = tid & 63;
  const int l15 = lane & 15;
  const int g = lane >> 4;
  const int wid = tid >> 6;
  const int wr = (wid >> 1) * 64;
  const int wc = (wid & 1) * 64;
  const int m0 = blockIdx.x * 128;
  const int n0 = blockIdx.y * 128;
  const int Kk = CD;

  f32x4 acc[4][4];
  #pragma unroll
  for (int i = 0; i < 4; ++i)
    #pragma unroll
    for (int j = 0; j < 4; ++j)
      acc[i][j] = (f32x4){0.f, 0.f, 0.f, 0.f};

  const int sr = tid >> 2;
  const int sc = (tid & 3) * 8;
  const bf16* aSrc = A + (size_t)(m0 + sr) * Kk + sc;
  const bf16* bSrc = Bt + (size_t)(n0 + sr) * Kk + sc;
  const int sOff = (tid & 192) * 8;

#define GSTAGE(bi, k0) do {                                             \
    gload_lds16(aSrc + (k0),                     &As[bi][sOff]);        \
    gload_lds16(aSrc + 64 * (size_t)Kk + (k0),   &As[bi][sOff + 2048]); \
    gload_lds16(bSrc + (k0),                     &Bs[bi][sOff]);        \
    gload_lds16(bSrc + 64 * (size_t)Kk + (k0),   &Bs[bi][sOff + 2048]); \
  } while (0)

  const int nt = Kk >> 5;
  int bi = 0;
  GSTAGE(0, 0);
  for (int t = 0; t < nt; ++t) {
    if (t + 1 < nt) {
      GSTAGE(bi ^ 1, (t + 1) * 32);
      asm volatile("s_waitcnt vmcnt(4)" ::: "memory");
    } else {
      asm volatile("s_waitcnt vmcnt(0)" ::: "memory");
    }
    __builtin_amdgcn_s_barrier();
    asm volatile("" ::: "memory");

    bf16x8 af[4], bfr[4];
    #pragma unroll
    for (int mt = 0; mt < 4; ++mt)
      af[mt] = *(const bf16x8*)&As[bi][(wr + mt * 16 + l15) * 32 + g * 8];
    #pragma unroll
    for (int nt2 = 0; nt2 < 4; ++nt2)
      bfr[nt2] = *(const bf16x8*)&Bs[bi][(wc + nt2 * 16 + l15) * 32 + g * 8];
    #pragma unroll
    for (int mt = 0; mt < 4; ++mt)
      #pragma unroll
      for (int nt2 = 0; nt2 < 4; ++nt2)
        acc[mt][nt2] = __builtin_amdgcn_mfma_f32_16x16x32_bf16(af[mt], bfr[nt2], acc[mt][nt2], 0, 0, 0);

    asm volatile("" ::: "memory");
    __builtin_amdgcn_s_barrier();
    bi ^= 1;
  }
#undef GSTAGE

  if (blockIdx.y < 10) {
    const bool isq = (blockIdx.y < 8);
    #pragma unroll
    for (int mt = 0; mt < 4; ++mt)
      #pragma unroll
      for (int r4 = 0; r4 < 4; ++r4) {
        int m = m0 + wr + mt * 16 + 4 * g + r4;
        int s = m & (CS - 1), bb = m >> 11;
        #pragma unroll
        for (int nt2 = 0; nt2 < 4; ++nt2) {
          int n = n0 + wc + nt2 * 16 + l15;
          int d = n & 63;
          float val = acc[mt][nt2][r4];
          float par = __shfl_xor(val, 1, 64);
          float cv = fc[s * 32 + (d >> 1)];
          float sv = fs[s * 32 + (d >> 1)];
          float o = (d & 1) ? (par * sv + val * cv) : (val * cv - par * sv);
          if (isq) {
            int h = n >> 6;
            ((unsigned short*)qb)[(((size_t)bb * CH + h) * CS + s) * CHD + d] = f2bf(o);
          } else {
            int kh = (n >> 6) - 16;
            ((unsigned short*)kb)[(((size_t)bb * CKH + kh) * CS + s) * CHD + d] = f2bf(o);
          }
        }
      }
  } else {
    #pragma unroll
    for (int mt = 0; mt < 4; ++mt) {
      int mb = m0 + wr + mt * 16 + 4 * g;
      int s0 = mb & (CS - 1), bb = mb >> 11;
      #pragma unroll
      for (int nt2 = 0; nt2 < 4; ++nt2) {
        int n = n0 + wc + nt2 * 16 + l15;
        int d = n & 63;
        int kh = (n >> 6) - 20;
        ushort4 pk = make_ushort4(f2bf(acc[mt][nt2][0]), f2bf(acc[mt][nt2][1]),
                                  f2bf(acc[mt][nt2][2]), f2bf(acc[mt][nt2][3]));
        *(ushort4*)&((unsigned short*)vt)[(((size_t)bb * CKH + kh) * CHD + d) * CS + s0] = pk;
      }
    }
  }
}

// ---------------------------------------------------------------------------
// Merged prep (R13-proven): conv_x (blocks 0..2047) + 4 weight transposes.
// ---------------------------------------------------------------------------
__global__ __launch_bounds__(256) void prep_kernel(
    const float* __restrict__ x, bf16* __restrict__ xb,
    const float* __restrict__ wq, const float* __restrict__ wk,
    const float* __restrict__ wv, const float* __restrict__ wo,
    bf16* __restrict__ wqkvt, bf16* __restrict__ wot)
{
  const int tid = threadIdx.x;
  int bid = blockIdx.x;
  if (bid < 2048) {
    int i = (bid * 256 + tid) * 8;
    float4 a = *(const float4*)&x[i];
    float4 b = *(const float4*)&x[i + 4];
    unsigned short* o = (unsigned short*)xb + i;
    *(ushort4*)o = make_ushort4(f2bf(a.x), f2bf(a.y), f2bf(a.z), f2bf(a.w));
    *(ushort4*)(o + 4) = make_ushort4(f2bf(b.x), f2bf(b.y), f2bf(b.z), f2bf(b.w));
    return;
  }
  bid -= 2048;
  const float* W; bf16* Wt; int Nn, bx, by;
  if (bid < 256)      { W = wq; Wt = wqkvt;                      Nn = 1024; bx = bid & 15;        by = bid >> 4; }
  else if (bid < 320) { W = wk; Wt = wqkvt + (size_t)1024 * CD;  Nn = 256;  bx = (bid-256) & 15;  by = (bid-256) >> 4; }
  else if (bid < 384) { W = wv; Wt = wqkvt + (size_t)1280 * CD;  Nn = 256;  bx = (bid-320) & 15;  by = (bid-320) >> 4; }
  else                { W = wo; Wt = wot;                        Nn = 1024; bx = (bid-384) & 15;  by = (bid-384) >> 4; }
  const int Kk = 1024;
  const int k0 = bx * 64;
  const int n0 = by * 64;

  __shared__ float T[64][65];
  const int lr = tid >> 4;
  const int lc = (tid & 15) * 4;
  #pragma unroll
  for (int i = 0; i < 4; ++i) {
    float4 v = *(const float4*)&W[(size_t)(k0 + lr + i * 16) * Nn + n0 + lc];
    T[lr + i * 16][lc + 0] = v.x;
    T[lr + i * 16][lc + 1] = v.y;
    T[lr + i * 16][lc + 2] = v.z;
    T[lr + i * 16][lc + 3] = v.w;
  }
  __syncthreads();
  const int rn = tid >> 3;
  const int ck = (tid & 7) * 8;
  #pragma unroll
  for (int i = 0; i < 2; ++i) {
    int nn = rn + i * 32;
    unsigned short u[8];
    #pragma unroll
    for (int e = 0; e < 8; ++e) u[e] = f2bf(T[ck + e][nn]);
    unsigned short* dst = (unsigned short*)Wt + (size_t)(n0 + nn) * Kk + k0 + ck;
    *(ushort4*)dst = make_ushort4(u[0], u[1], u[2], u[3]);
    *(ushort4*)(dst + 4) = make_ushort4(u[4], u[5], u[6], u[7]);
  }
}

__global__ void zero_flags_kernel(int* __restrict__ flags)
{
  flags[threadIdx.x] = 0;
}

// ---------------------------------------------------------------------------
// MFMA flash attention, cross-block split-KV x2. Body = R8-proven kernel;
// deltas: (1) tile range [tbeg,tend) per chunk (chunk1 owns diagonal);
// (2) epilogue writes unnormalized-O bf16 + (m,l) partials (chunk1 -> o_b's
// final layout, chunk0 -> oc0), then threadfence + device atomicAdd flag;
// the SECOND arriver (no waiting -> no deadlock) merges partner partials
// with its own registers and writes final o_b. Canonical chunk-ordered FMA
// => deterministic. Grid 1024 (pairs adjacent, longest first); 50KB LDS ->
// 3 blocks/CU resident.
// ---------------------------------------------------------------------------
__global__ __launch_bounds__(256, 2) void flash_split_kernel(
    const bf16* __restrict__ qb, const bf16* __restrict__ kb,
    const bf16* __restrict__ vt, bf16* __restrict__ oc0,
    bf16* __restrict__ ob, float2* __restrict__ ml, int* __restrict__ flags)
{
  __shared__ __align__(16) char arena[51200];
  __shared__ int sflag;
  char* KL = arena;                       // [2][8192]: K tile 64x(64 bf16)
  char* VL = arena + 16384;               // [2][8192]: V^T tile 64x(64 bf16)
  const int tid = threadIdx.x;
  const int lane = tid & 63;
  const int wid = tid >> 6;
  unsigned short* PLW = (unsigned short*)(arena + 32768) + wid * 2304; // [32][72]
  const int l15 = lane & 15;
  const int g = lane >> 4;
  const int blk = blockIdx.x;
  const int chunk = blk & 1;
  const int grp = (blk >> 1) & 7;         // b*4+kh
  const int idx = blk >> 4;               // 0..63
  const int qt = 63 - idx;                // longest pairs first
  const int kh = grp & 3;
  const int b = grp >> 2;
  const int h = kh * CREP + wid;
  const int N64 = (qt >> 1) + 1;
  const int hc = N64 >> 1;
  const int tbeg = chunk ? hc : 0;
  const int tend = chunk ? N64 : hc;
  const float SC = 0.18033688f;           // 0.125 * log2(e)

  const bf16* qbase = qb + ((size_t)(b * CH + h) * CS + qt * 32) * CHD;
  const bf16* kbase = kb + (size_t)(b * CKH + kh) * CS * CHD;
  const bf16* vbase = vt + (size_t)(b * CKH + kh) * CHD * CS;  // [d][s]

  bf16x8 qf[2][2];
  #pragma unroll
  for (int qs = 0; qs < 2; ++qs)
    #pragma unroll
    for (int c = 0; c < 2; ++c)
      qf[qs][c] = *(const bf16x8*)(qbase + (qs * 16 + l15) * CHD + c * 32 + g * 8);

  bf16x8 ones;
  #pragma unroll
  for (int e = 0; e < 8; ++e) ones[e] = (short)0x3F80;  // bf16 1.0

  f32x4 oacc[2][4];
  f32x4 lacc[2];
  #pragma unroll
  for (int qs = 0; qs < 2; ++qs) {
    lacc[qs] = (f32x4){0.f, 0.f, 0.f, 0.f};
    #pragma unroll
    for (int dt = 0; dt < 4; ++dt)
      oacc[qs][dt] = (f32x4){0.f, 0.f, 0.f, 0.f};
  }
  float mrow[2] = {-1e30f, -1e30f};

  const int slr = tid >> 3;
  const int scg = (tid & 7) ^ (slr & 7);
  const bf16* kstage = kbase + (size_t)slr * CHD + scg * 8;
  const bf16* vstage = vbase + (size_t)slr * CS + scg * 8;
  char* kdst = KL + wid * 1024;
  char* vdst = VL + wid * 1024;

#define STAGE(bi, t64) do {                                        \
    const bf16* ks_ = kstage + (size_t)(t64) * 64 * CHD;           \
    const bf16* vs_ = vstage + (t64) * 64;                         \
    gload_lds16(ks_,            kdst + (bi) * 8192);               \
    gload_lds16(ks_ + 32 * CHD, kdst + (bi) * 8192 + 4096);        \
    gload_lds16(vs_,            vdst + (bi) * 8192);               \
    gload_lds16(vs_ + 32 * CS,  vdst + (bi) * 8192 + 4096);        \
  } while (0)

  if (tbeg < tend) {
    int bi = 0;
    STAGE(0, tbeg);
    for (int t = tbeg; t < tend; ++t) {
      if (t + 1 < tend) {
        STAGE(bi ^ 1, t + 1);
        asm volatile("s_waitcnt vmcnt(4)" ::: "memory");
      } else {
        asm volatile("s_waitcnt vmcnt(0)" ::: "memory");
      }
      __builtin_amdgcn_s_barrier();
      asm volatile("" ::: "memory");

      const char* KB = KL + bi * 8192;
      const char* VB = VL + bi * 8192;
      bf16x8 kfr[4][2], vfr[4][2];
      #pragma unroll
      for (int kt = 0; kt < 4; ++kt) {
        int row = kt * 16 + l15;
        #pragma unroll
        for (int c = 0; c < 2; ++c)
          kfr[kt][c] = *(const bf16x8*)(KB + row * 128 + (((c * 4 + g) ^ (row & 7)) << 4));
      }
      #pragma unroll
      for (int dt = 0; dt < 4; ++dt) {
        int row = dt * 16 + l15;
        #pragma unroll
        for (int st = 0; st < 2; ++st)
          vfr[dt][st] = *(const bf16x8*)(VB + row * 128 + (((st * 4 + g) ^ (row & 7)) << 4));
      }

      // QK^T (swapped): S^T[k][q]
      f32x4 sacc[4][2];
      #pragma unroll
      for (int kt = 0; kt < 4; ++kt)
        #pragma unroll
        for (int qs = 0; qs < 2; ++qs)
          sacc[kt][qs] = (f32x4){0.f, 0.f, 0.f, 0.f};
      #pragma unroll
      for (int c = 0; c < 2; ++c)
        #pragma unroll
        for (int kt = 0; kt < 4; ++kt)
          #pragma unroll
          for (int qs = 0; qs < 2; ++qs)
            sacc[kt][qs] = __builtin_amdgcn_mfma_f32_16x16x32_bf16(kfr[kt][c], qf[qs][c], sacc[kt][qs], 0, 0, 0);

      const bool diag = (t == N64 - 1);   // only reachable in chunk1
      #pragma unroll
      for (int qs = 0; qs < 2; ++qs) {
        float e[16];
        float pm = -1e30f;
        #pragma unroll
        for (int kt = 0; kt < 4; ++kt)
          #pragma unroll
          for (int r = 0; r < 4; ++r) {
            float v = sacc[kt][qs][r] * SC;
            if (diag) {
              int koff = t * 64 + kt * 16 + 4 * g + r;
              if (koff > qt * 32 + qs * 16 + l15) v = -1e30f;
            }
            e[kt * 4 + r] = v;
            pm = fmaxf(pm, v);
          }
        if (__any(pm > mrow[qs] + 8.0f)) {       // slow path: exact rescale
          pm = fmaxf(pm, __shfl_xor(pm, 16, 64));
          pm = fmaxf(pm, __shfl_xor(pm, 32, 64));
          float nm = fmaxf(mrow[qs], pm);
          float corr = exp2f(mrow[qs] - nm);
          mrow[qs] = nm;
          lacc[qs] *= corr;
          #pragma unroll
          for (int dt = 0; dt < 4; ++dt) oacc[qs][dt] *= corr;
        }
        unsigned short pb[16];
        #pragma unroll
        for (int i = 0; i < 16; ++i)
          pb[i] = f2bf(exp2f(e[i] - mrow[qs]));  // p <= 2^8
        #pragma unroll
        for (int kt = 0; kt < 4; ++kt)
          *(ushort4*)&PLW[(qs * 16 + l15) * 72 + kt * 16 + 4 * g] =
              make_ushort4(pb[kt * 4 + 0], pb[kt * 4 + 1], pb[kt * 4 + 2], pb[kt * 4 + 3]);
      }

      // PV + psum (same-wave LDS RAW)
      #pragma unroll
      for (int qs = 0; qs < 2; ++qs) {
        #pragma unroll
        for (int st = 0; st < 2; ++st) {
          bf16x8 pf = *(const bf16x8*)&PLW[(qs * 16 + l15) * 72 + st * 32 + g * 8];
          lacc[qs] = __builtin_amdgcn_mfma_f32_16x16x32_bf16(ones, pf, lacc[qs], 0, 0, 0);
          #pragma unroll
          for (int dt = 0; dt < 4; ++dt)
            oacc[qs][dt] = __builtin_amdgcn_mfma_f32_16x16x32_bf16(vfr[dt][st], pf, oacc[qs][dt], 0, 0, 0);
        }
      }

      asm volatile("" ::: "memory");
      __builtin_amdgcn_s_barrier();
      bi ^= 1;
    }
  }
#undef STAGE

  // ---- partial write (unnormalized O, bf16) + (m,l) ----
  unsigned short* pdst = (unsigned short*)(chunk ? ob : oc0);
  #pragma unroll
  for (int qs = 0; qs < 2; ++qs) {
    int qg = qt * 32 + qs * 16 + l15;
    unsigned short* prow = pdst + (size_t)(b * CS + qg) * CNQ + h * CHD;
    #pragma unroll
    for (int dt = 0; dt < 4; ++dt)
      *(ushort4*)&prow[dt * 16 + 4 * g] =
          make_ushort4(f2bf(oacc[qs][dt][0]), f2bf(oacc[qs][dt][1]),
                       f2bf(oacc[qs][dt][2]), f2bf(oacc[qs][dt][3]));
    if (g == 0)
      ml[(((size_t)chunk * CB + b) * CH + h) * CS + qg] = make_float2(mrow[qs], lacc[qs][0]);
  }
  __threadfence();     // release: partials visible device-wide before flag
  __syncthreads();
  if (tid == 0) sflag = atomicAdd(&flags[blk >> 1], 1);
  __syncthreads();
  if (sflag == 1) {
    __threadfence();   // acquire: partner's partials
    const unsigned short* psrc = (const unsigned short*)(chunk ? oc0 : ob);
    #pragma unroll
    for (int qs = 0; qs < 2; ++qs) {
      int qg = qt * 32 + qs * 16 + l15;
      float2 mlp = ml[(((size_t)(chunk ^ 1) * CB + b) * CH + h) * CS + qg];
      // canonical order: A = chunk0 values, B = chunk1 values
      float mA = chunk ? mlp.x : mrow[qs];
      float lA = chunk ? mlp.y : lacc[qs][0];
      float mB = chunk ? mrow[qs] : mlp.x;
      float lB = chunk ? lacc[qs][0] : mlp.y;
      float M = fmaxf(mA, mB);
      float cA = exp2f(mA - M), cB = exp2f(mB - M);
      float inv = 1.0f / (cA * lA + cB * lB);
      const unsigned short* srow = psrc + (size_t)(b * CS + qg) * CNQ + h * CHD;
      unsigned short* orow = (unsigned short*)ob + (size_t)(b * CS + qg) * CNQ + h * CHD;
      #pragma unroll
      for (int dt = 0; dt < 4; ++dt) {
        ushort4 pv = *(const ushort4*)&srow[dt * 16 + 4 * g];
        float pf4[4] = {bf2f(pv.x), bf2f(pv.y), bf2f(pv.z), bf2f(pv.w)};
        ushort4 o4;
        unsigned short* op = &o4.x;
        #pragma unroll
        for (int r = 0; r < 4; ++r) {
          float own = oacc[qs][dt][r];
          float vA = chunk ? pf4[r] : own;
          float vB = chunk ? own : pf4[r];
          op[r] = f2bf((cA * vA + cB * vB) * inv);
        }
        *(ushort4*)&orow[dt * 16 + 4 * g] = o4;
      }
    }
  }
}

// ---------------------------------------------------------------------------
extern "C" void kernel_launch(void* const* d_in, const int* in_sizes, int n_in,
                              void* d_out, int out_size, void* d_ws, size_t ws_size,
                              hipStream_t stream)
{
  const float* x  = (const float*)d_in[0];
  const float* wq = (const float*)d_in[1];
  const float* wk = (const float*)d_in[2];
  const float* wv = (const float*)d_in[3];
  const float* wo = (const float*)d_in[4];
  const float* fc = (const float*)d_in[5];
  const float* fs = (const float*)d_in[6];
  float* out = (float*)d_out;

  char* ws = (char*)d_ws;
  // workspace (peak ~35.7MB):
  //   [0, 8M):        x_b (dead after qkv GEMM) -> o_b / chunk1 partial
  //   [8M, 11M):      wqkvt (dead after qkv GEMM)
  //   [11M, 13M):     wot
  //   [13M, 21M):     q_b
  //   [21M, 23M):     k_b
  //   [23M, 25M):     v_t
  //   [25M, 33M):     oc0 (chunk0 partial)
  //   [33M, 34M):     ml  [2][B][H][S] float2
  //   [34M, +2KB):    flags [512] int
  bf16*   x_b   = (bf16*)(ws);
  bf16*   wqkvt = (bf16*)(ws + 8388608);
  bf16*   wot   = (bf16*)(ws + 11534336);
  bf16*   q_b   = (bf16*)(ws + 13631488);
  bf16*   k_b   = (bf16*)(ws + 22020096);
  bf16*   v_t   = (bf16*)(ws + 24117248);
  bf16*   o_b   = (bf16*)(ws);               // over x_b
  bf16*   oc0   = (bf16*)(ws + 26214400);
  float2* mlb   = (float2*)(ws + 34603008);
  int*    flags = (int*)(ws + 35651584);

  prep_kernel<<<2688, 256, 0, stream>>>(x, x_b, wq, wk, wv, wo, wqkvt, wot);
  gemm_qkv_rope_kernel<<<dim3(32, 12), 256, 0, stream>>>(x_b, wqkvt, fc, fs, q_b, k_b, v_t);
  zero_flags_kernel<<<1, 512, 0, stream>>>(flags);
  flash_split_kernel<<<1024, 256, 0, stream>>>(q_b, k_b, v_t, oc0, o_b, mlb, flags);
  gemm_mfma_kernel<<<dim3(32, 8), 256, 0, stream>>>(o_b, wot, out, CM, CD, CNQ, CNQ);
}

// Round 15
// 129.162 us; speedup vs baseline: 2.8226x; 2.8226x over previous
//
#include <hip/hip_runtime.h>
#include <hip/hip_bf16.h>

using bf16 = __hip_bfloat16;
typedef short bf16x8 __attribute__((ext_vector_type(8)));
typedef float f32x4 __attribute__((ext_vector_type(4)));

#define CB 2
#define CS 2048
#define CD 1024
#define CH 16
#define CKH 4
#define CHD 64
#define CREP 4
#define CNQ (CH*CHD)    // 1024
#define CNKV (CKH*CHD)  // 256
#define CM (CB*CS)      // 4096

__device__ __forceinline__ unsigned short f2bf(float f) {
  union { float f; unsigned int i; } c; c.f = f;
  unsigned int r = c.i + 0x7FFFu + ((c.i >> 16) & 1u);  // RNE
  return (unsigned short)(r >> 16);
}
__device__ __forceinline__ float bf2f(unsigned short u) {
  union { unsigned int i; float f; } c;
  c.i = ((unsigned int)u) << 16;
  return c.f;
}
__device__ __forceinline__ void gload_lds16(const void* g, void* l) {
  __builtin_amdgcn_global_load_lds(
      (const __attribute__((address_space(1))) void*)g,
      (__attribute__((address_space(3))) void*)l, 16, 0, 0);
}

// ---------------------------------------------------------------------------
// bf16 MFMA GEMM v2 (R8-proven): C[M,N] f32 = A[M,K](lda) · Bt[N,K]^T.
// ---------------------------------------------------------------------------
__global__ __launch_bounds__(256) void gemm_mfma_kernel(
    const bf16* __restrict__ A, const bf16* __restrict__ Bt,
    float* __restrict__ C, int Mm, int Nn, int Kk, int lda)
{
  __shared__ __align__(16) bf16 As[2][128 * 32];
  __shared__ __align__(16) bf16 Bs[2][128 * 32];
  const int tid = threadIdx.x;
  const int lane = tid & 63;
  const int l15 = lane & 15;
  const int g = lane >> 4;
  const int wid = tid >> 6;
  const int wr = (wid >> 1) * 64;
  const int wc = (wid & 1) * 64;
  const int m0 = blockIdx.x * 128;
  const int n0 = blockIdx.y * 128;

  f32x4 acc[4][4];
  #pragma unroll
  for (int i = 0; i < 4; ++i)
    #pragma unroll
    for (int j = 0; j < 4; ++j)
      acc[i][j] = (f32x4){0.f, 0.f, 0.f, 0.f};

  const int sr = tid >> 2;
  const int sc = (tid & 3) * 8;
  const bf16* aSrc = A + (size_t)(m0 + sr) * lda + sc;
  const bf16* bSrc = Bt + (size_t)(n0 + sr) * Kk + sc;
  const int sOff = (tid & 192) * 8;

#define GSTAGE(bi, k0) do {                                             \
    gload_lds16(aSrc + (k0),                     &As[bi][sOff]);        \
    gload_lds16(aSrc + 64 * (size_t)lda + (k0),  &As[bi][sOff + 2048]); \
    gload_lds16(bSrc + (k0),                     &Bs[bi][sOff]);        \
    gload_lds16(bSrc + 64 * (size_t)Kk + (k0),   &Bs[bi][sOff + 2048]); \
  } while (0)

  const int nt = Kk >> 5;
  int bi = 0;
  GSTAGE(0, 0);
  for (int t = 0; t < nt; ++t) {
    if (t + 1 < nt) {
      GSTAGE(bi ^ 1, (t + 1) * 32);
      asm volatile("s_waitcnt vmcnt(4)" ::: "memory");
    } else {
      asm volatile("s_waitcnt vmcnt(0)" ::: "memory");
    }
    __builtin_amdgcn_s_barrier();
    asm volatile("" ::: "memory");

    bf16x8 af[4], bfr[4];
    #pragma unroll
    for (int mt = 0; mt < 4; ++mt)
      af[mt] = *(const bf16x8*)&As[bi][(wr + mt * 16 + l15) * 32 + g * 8];
    #pragma unroll
    for (int nt2 = 0; nt2 < 4; ++nt2)
      bfr[nt2] = *(const bf16x8*)&Bs[bi][(wc + nt2 * 16 + l15) * 32 + g * 8];
    #pragma unroll
    for (int mt = 0; mt < 4; ++mt)
      #pragma unroll
      for (int nt2 = 0; nt2 < 4; ++nt2)
        acc[mt][nt2] = __builtin_amdgcn_mfma_f32_16x16x32_bf16(af[mt], bfr[nt2], acc[mt][nt2], 0, 0, 0);

    asm volatile("" ::: "memory");
    __builtin_amdgcn_s_barrier();
    bi ^= 1;
  }
#undef GSTAGE

  #pragma unroll
  for (int mt = 0; mt < 4; ++mt)
    #pragma unroll
    for (int r4 = 0; r4 < 4; ++r4) {
      const size_t row = (size_t)(m0 + wr + mt * 16 + 4 * g + r4);
      #pragma unroll
      for (int nt2 = 0; nt2 < 4; ++nt2)
        C[row * Nn + n0 + wc + nt2 * 16 + l15] = acc[mt][nt2][r4];
    }
}

// ---------------------------------------------------------------------------
// qkv GEMM with fused RoPE + layout epilogue (R12-proven).
// ---------------------------------------------------------------------------
__global__ __launch_bounds__(256) void gemm_qkv_rope_kernel(
    const bf16* __restrict__ A, const bf16* __restrict__ Bt,
    const float* __restrict__ fc, const float* __restrict__ fs,
    bf16* __restrict__ qb, bf16* __restrict__ kb, bf16* __restrict__ vt)
{
  __shared__ __align__(16) bf16 As[2][128 * 32];
  __shared__ __align__(16) bf16 Bs[2][128 * 32];
  const int tid = threadIdx.x;
  const int lane = tid & 63;
  const int l15 = lane & 15;
  const int g = lane >> 4;
  const int wid = tid >> 6;
  const int wr = (wid >> 1) * 64;
  const int wc = (wid & 1) * 64;
  const int m0 = blockIdx.x * 128;
  const int n0 = blockIdx.y * 128;
  const int Kk = CD;

  f32x4 acc[4][4];
  #pragma unroll
  for (int i = 0; i < 4; ++i)
    #pragma unroll
    for (int j = 0; j < 4; ++j)
      acc[i][j] = (f32x4){0.f, 0.f, 0.f, 0.f};

  const int sr = tid >> 2;
  const int sc = (tid & 3) * 8;
  const bf16* aSrc = A + (size_t)(m0 + sr) * Kk + sc;
  const bf16* bSrc = Bt + (size_t)(n0 + sr) * Kk + sc;
  const int sOff = (tid & 192) * 8;

#define GSTAGE(bi, k0) do {                                             \
    gload_lds16(aSrc + (k0),                     &As[bi][sOff]);        \
    gload_lds16(aSrc + 64 * (size_t)Kk + (k0),   &As[bi][sOff + 2048]); \
    gload_lds16(bSrc + (k0),                     &Bs[bi][sOff]);        \
    gload_lds16(bSrc + 64 * (size_t)Kk + (k0),   &Bs[bi][sOff + 2048]); \
  } while (0)

  const int nt = Kk >> 5;
  int bi = 0;
  GSTAGE(0, 0);
  for (int t = 0; t < nt; ++t) {
    if (t + 1 < nt) {
      GSTAGE(bi ^ 1, (t + 1) * 32);
      asm volatile("s_waitcnt vmcnt(4)" ::: "memory");
    } else {
      asm volatile("s_waitcnt vmcnt(0)" ::: "memory");
    }
    __builtin_amdgcn_s_barrier();
    asm volatile("" ::: "memory");

    bf16x8 af[4], bfr[4];
    #pragma unroll
    for (int mt = 0; mt < 4; ++mt)
      af[mt] = *(const bf16x8*)&As[bi][(wr + mt * 16 + l15) * 32 + g * 8];
    #pragma unroll
    for (int nt2 = 0; nt2 < 4; ++nt2)
      bfr[nt2] = *(const bf16x8*)&Bs[bi][(wc + nt2 * 16 + l15) * 32 + g * 8];
    #pragma unroll
    for (int mt = 0; mt < 4; ++mt)
      #pragma unroll
      for (int nt2 = 0; nt2 < 4; ++nt2)
        acc[mt][nt2] = __builtin_amdgcn_mfma_f32_16x16x32_bf16(af[mt], bfr[nt2], acc[mt][nt2], 0, 0, 0);

    asm volatile("" ::: "memory");
    __builtin_amdgcn_s_barrier();
    bi ^= 1;
  }
#undef GSTAGE

  if (blockIdx.y < 10) {
    const bool isq = (blockIdx.y < 8);
    #pragma unroll
    for (int mt = 0; mt < 4; ++mt)
      #pragma unroll
      for (int r4 = 0; r4 < 4; ++r4) {
        int m = m0 + wr + mt * 16 + 4 * g + r4;
        int s = m & (CS - 1), bb = m >> 11;
        #pragma unroll
        for (int nt2 = 0; nt2 < 4; ++nt2) {
          int n = n0 + wc + nt2 * 16 + l15;
          int d = n & 63;
          float val = acc[mt][nt2][r4];
          float par = __shfl_xor(val, 1, 64);
          float cv = fc[s * 32 + (d >> 1)];
          float sv = fs[s * 32 + (d >> 1)];
          float o = (d & 1) ? (par * sv + val * cv) : (val * cv - par * sv);
          if (isq) {
            int h = n >> 6;
            ((unsigned short*)qb)[(((size_t)bb * CH + h) * CS + s) * CHD + d] = f2bf(o);
          } else {
            int kh = (n >> 6) - 16;
            ((unsigned short*)kb)[(((size_t)bb * CKH + kh) * CS + s) * CHD + d] = f2bf(o);
          }
        }
      }
  } else {
    #pragma unroll
    for (int mt = 0; mt < 4; ++mt) {
      int mb = m0 + wr + mt * 16 + 4 * g;
      int s0 = mb & (CS - 1), bb = mb >> 11;
      #pragma unroll
      for (int nt2 = 0; nt2 < 4; ++nt2) {
        int n = n0 + wc + nt2 * 16 + l15;
        int d = n & 63;
        int kh = (n >> 6) - 20;
        ushort4 pk = make_ushort4(f2bf(acc[mt][nt2][0]), f2bf(acc[mt][nt2][1]),
                                  f2bf(acc[mt][nt2][2]), f2bf(acc[mt][nt2][3]));
        *(ushort4*)&((unsigned short*)vt)[(((size_t)bb * CKH + kh) * CHD + d) * CS + s0] = pk;
      }
    }
  }
}

// ---------------------------------------------------------------------------
// Merged prep (R13-proven): conv_x (blocks 0..2047) + 4 weight transposes.
// ---------------------------------------------------------------------------
__global__ __launch_bounds__(256) void prep_kernel(
    const float* __restrict__ x, bf16* __restrict__ xb,
    const float* __restrict__ wq, const float* __restrict__ wk,
    const float* __restrict__ wv, const float* __restrict__ wo,
    bf16* __restrict__ wqkvt, bf16* __restrict__ wot)
{
  const int tid = threadIdx.x;
  int bid = blockIdx.x;
  if (bid < 2048) {
    int i = (bid * 256 + tid) * 8;
    float4 a = *(const float4*)&x[i];
    float4 b = *(const float4*)&x[i + 4];
    unsigned short* o = (unsigned short*)xb + i;
    *(ushort4*)o = make_ushort4(f2bf(a.x), f2bf(a.y), f2bf(a.z), f2bf(a.w));
    *(ushort4*)(o + 4) = make_ushort4(f2bf(b.x), f2bf(b.y), f2bf(b.z), f2bf(b.w));
    return;
  }
  bid -= 2048;
  const float* W; bf16* Wt; int Nn, bx, by;
  if (bid < 256)      { W = wq; Wt = wqkvt;                      Nn = 1024; bx = bid & 15;        by = bid >> 4; }
  else if (bid < 320) { W = wk; Wt = wqkvt + (size_t)1024 * CD;  Nn = 256;  bx = (bid-256) & 15;  by = (bid-256) >> 4; }
  else if (bid < 384) { W = wv; Wt = wqkvt + (size_t)1280 * CD;  Nn = 256;  bx = (bid-320) & 15;  by = (bid-320) >> 4; }
  else                { W = wo; Wt = wot;                        Nn = 1024; bx = (bid-384) & 15;  by = (bid-384) >> 4; }
  const int Kk = 1024;
  const int k0 = bx * 64;
  const int n0 = by * 64;

  __shared__ float T[64][65];
  const int lr = tid >> 4;
  const int lc = (tid & 15) * 4;
  #pragma unroll
  for (int i = 0; i < 4; ++i) {
    float4 v = *(const float4*)&W[(size_t)(k0 + lr + i * 16) * Nn + n0 + lc];
    T[lr + i * 16][lc + 0] = v.x;
    T[lr + i * 16][lc + 1] = v.y;
    T[lr + i * 16][lc + 2] = v.z;
    T[lr + i * 16][lc + 3] = v.w;
  }
  __syncthreads();
  const int rn = tid >> 3;
  const int ck = (tid & 7) * 8;
  #pragma unroll
  for (int i = 0; i < 2; ++i) {
    int nn = rn + i * 32;
    unsigned short u[8];
    #pragma unroll
    for (int e = 0; e < 8; ++e) u[e] = f2bf(T[ck + e][nn]);
    unsigned short* dst = (unsigned short*)Wt + (size_t)(n0 + nn) * Kk + k0 + ck;
    *(ushort4*)dst = make_ushort4(u[0], u[1], u[2], u[3]);
    *(ushort4*)(dst + 4) = make_ushort4(u[4], u[5], u[6], u[7]);
  }
}

// ---------------------------------------------------------------------------
// MFMA flash attention, cross-block split-KV x2 — NO fences/atomics.
// Both chunks write unnormalized-O bf16 partials (chunk1 -> ob, chunk0 ->
// oc0) + (m,l); the kernel-boundary synchronizes; merge_kernel combines.
// (R14's in-kernel fence merge caused device-wide L2 writeback storms.)
// ---------------------------------------------------------------------------
__global__ __launch_bounds__(256, 2) void flash_split_kernel(
    const bf16* __restrict__ qb, const bf16* __restrict__ kb,
    const bf16* __restrict__ vt, bf16* __restrict__ oc0,
    bf16* __restrict__ ob, float2* __restrict__ ml)
{
  __shared__ __align__(16) char arena[51200];
  char* KL = arena;                       // [2][8192]: K tile 64x(64 bf16)
  char* VL = arena + 16384;               // [2][8192]: V^T tile 64x(64 bf16)
  const int tid = threadIdx.x;
  const int lane = tid & 63;
  const int wid = tid >> 6;
  unsigned short* PLW = (unsigned short*)(arena + 32768) + wid * 2304; // [32][72]
  const int l15 = lane & 15;
  const int g = lane >> 4;
  const int blk = blockIdx.x;
  const int chunk = blk & 1;
  const int grp = (blk >> 1) & 7;         // b*4+kh
  const int idx = blk >> 4;               // 0..63
  const int qt = 63 - idx;                // longest pairs first
  const int kh = grp & 3;
  const int b = grp >> 2;
  const int h = kh * CREP + wid;
  const int N64 = (qt >> 1) + 1;
  const int hc = N64 >> 1;
  const int tbeg = chunk ? hc : 0;
  const int tend = chunk ? N64 : hc;
  const float SC = 0.18033688f;           // 0.125 * log2(e)

  const bf16* qbase = qb + ((size_t)(b * CH + h) * CS + qt * 32) * CHD;
  const bf16* kbase = kb + (size_t)(b * CKH + kh) * CS * CHD;
  const bf16* vbase = vt + (size_t)(b * CKH + kh) * CHD * CS;  // [d][s]

  bf16x8 qf[2][2];
  #pragma unroll
  for (int qs = 0; qs < 2; ++qs)
    #pragma unroll
    for (int c = 0; c < 2; ++c)
      qf[qs][c] = *(const bf16x8*)(qbase + (qs * 16 + l15) * CHD + c * 32 + g * 8);

  bf16x8 ones;
  #pragma unroll
  for (int e = 0; e < 8; ++e) ones[e] = (short)0x3F80;  // bf16 1.0

  f32x4 oacc[2][4];
  f32x4 lacc[2];
  #pragma unroll
  for (int qs = 0; qs < 2; ++qs) {
    lacc[qs] = (f32x4){0.f, 0.f, 0.f, 0.f};
    #pragma unroll
    for (int dt = 0; dt < 4; ++dt)
      oacc[qs][dt] = (f32x4){0.f, 0.f, 0.f, 0.f};
  }
  float mrow[2] = {-1e30f, -1e30f};

  const int slr = tid >> 3;
  const int scg = (tid & 7) ^ (slr & 7);
  const bf16* kstage = kbase + (size_t)slr * CHD + scg * 8;
  const bf16* vstage = vbase + (size_t)slr * CS + scg * 8;
  char* kdst = KL + wid * 1024;
  char* vdst = VL + wid * 1024;

#define STAGE(bi, t64) do {                                        \
    const bf16* ks_ = kstage + (size_t)(t64) * 64 * CHD;           \
    const bf16* vs_ = vstage + (t64) * 64;                         \
    gload_lds16(ks_,            kdst + (bi) * 8192);               \
    gload_lds16(ks_ + 32 * CHD, kdst + (bi) * 8192 + 4096);        \
    gload_lds16(vs_,            vdst + (bi) * 8192);               \
    gload_lds16(vs_ + 32 * CS,  vdst + (bi) * 8192 + 4096);        \
  } while (0)

  if (tbeg < tend) {
    int bi = 0;
    STAGE(0, tbeg);
    for (int t = tbeg; t < tend; ++t) {
      if (t + 1 < tend) {
        STAGE(bi ^ 1, t + 1);
        asm volatile("s_waitcnt vmcnt(4)" ::: "memory");
      } else {
        asm volatile("s_waitcnt vmcnt(0)" ::: "memory");
      }
      __builtin_amdgcn_s_barrier();
      asm volatile("" ::: "memory");

      const char* KB = KL + bi * 8192;
      const char* VB = VL + bi * 8192;
      bf16x8 kfr[4][2], vfr[4][2];
      #pragma unroll
      for (int kt = 0; kt < 4; ++kt) {
        int row = kt * 16 + l15;
        #pragma unroll
        for (int c = 0; c < 2; ++c)
          kfr[kt][c] = *(const bf16x8*)(KB + row * 128 + (((c * 4 + g) ^ (row & 7)) << 4));
      }
      #pragma unroll
      for (int dt = 0; dt < 4; ++dt) {
        int row = dt * 16 + l15;
        #pragma unroll
        for (int st = 0; st < 2; ++st)
          vfr[dt][st] = *(const bf16x8*)(VB + row * 128 + (((st * 4 + g) ^ (row & 7)) << 4));
      }

      // QK^T (swapped): S^T[k][q]
      f32x4 sacc[4][2];
      #pragma unroll
      for (int kt = 0; kt < 4; ++kt)
        #pragma unroll
        for (int qs = 0; qs < 2; ++qs)
          sacc[kt][qs] = (f32x4){0.f, 0.f, 0.f, 0.f};
      #pragma unroll
      for (int c = 0; c < 2; ++c)
        #pragma unroll
        for (int kt = 0; kt < 4; ++kt)
          #pragma unroll
          for (int qs = 0; qs < 2; ++qs)
            sacc[kt][qs] = __builtin_amdgcn_mfma_f32_16x16x32_bf16(kfr[kt][c], qf[qs][c], sacc[kt][qs], 0, 0, 0);

      const bool diag = (t == N64 - 1);   // only reachable in chunk1
      #pragma unroll
      for (int qs = 0; qs < 2; ++qs) {
        float e[16];
        float pm = -1e30f;
        #pragma unroll
        for (int kt = 0; kt < 4; ++kt)
          #pragma unroll
          for (int r = 0; r < 4; ++r) {
            float v = sacc[kt][qs][r] * SC;
            if (diag) {
              int koff = t * 64 + kt * 16 + 4 * g + r;
              if (koff > qt * 32 + qs * 16 + l15) v = -1e30f;
            }
            e[kt * 4 + r] = v;
            pm = fmaxf(pm, v);
          }
        if (__any(pm > mrow[qs] + 8.0f)) {       // slow path: exact rescale
          pm = fmaxf(pm, __shfl_xor(pm, 16, 64));
          pm = fmaxf(pm, __shfl_xor(pm, 32, 64));
          float nm = fmaxf(mrow[qs], pm);
          float corr = exp2f(mrow[qs] - nm);
          mrow[qs] = nm;
          lacc[qs] *= corr;
          #pragma unroll
          for (int dt = 0; dt < 4; ++dt) oacc[qs][dt] *= corr;
        }
        unsigned short pb[16];
        #pragma unroll
        for (int i = 0; i < 16; ++i)
          pb[i] = f2bf(exp2f(e[i] - mrow[qs]));  // p <= 2^8
        #pragma unroll
        for (int kt = 0; kt < 4; ++kt)
          *(ushort4*)&PLW[(qs * 16 + l15) * 72 + kt * 16 + 4 * g] =
              make_ushort4(pb[kt * 4 + 0], pb[kt * 4 + 1], pb[kt * 4 + 2], pb[kt * 4 + 3]);
      }

      // PV + psum (same-wave LDS RAW)
      #pragma unroll
      for (int qs = 0; qs < 2; ++qs) {
        #pragma unroll
        for (int st = 0; st < 2; ++st) {
          bf16x8 pf = *(const bf16x8*)&PLW[(qs * 16 + l15) * 72 + st * 32 + g * 8];
          lacc[qs] = __builtin_amdgcn_mfma_f32_16x16x32_bf16(ones, pf, lacc[qs], 0, 0, 0);
          #pragma unroll
          for (int dt = 0; dt < 4; ++dt)
            oacc[qs][dt] = __builtin_amdgcn_mfma_f32_16x16x32_bf16(vfr[dt][st], pf, oacc[qs][dt], 0, 0, 0);
        }
      }

      asm volatile("" ::: "memory");
      __builtin_amdgcn_s_barrier();
      bi ^= 1;
    }
  }
#undef STAGE

  // partial write: unnormalized O (bf16) + (m,l). Kernel boundary = sync.
  unsigned short* pdst = (unsigned short*)(chunk ? ob : oc0);
  #pragma unroll
  for (int qs = 0; qs < 2; ++qs) {
    int qg = qt * 32 + qs * 16 + l15;
    unsigned short* prow = pdst + (size_t)(b * CS + qg) * CNQ + h * CHD;
    #pragma unroll
    for (int dt = 0; dt < 4; ++dt)
      *(ushort4*)&prow[dt * 16 + 4 * g] =
          make_ushort4(f2bf(oacc[qs][dt][0]), f2bf(oacc[qs][dt][1]),
                       f2bf(oacc[qs][dt][2]), f2bf(oacc[qs][dt][3]));
    if (g == 0)
      ml[(((size_t)chunk * CB + b) * CH + h) * CS + qg] = make_float2(mrow[qs], lacc[qs][0]);
  }
}

// ---------------------------------------------------------------------------
// Merge: final_o[row][col] = (c0*o0 + c1*o1) / (c0*l0 + c1*l1), written
// in-place over ob (chunk1 partial). 8 bf16 per thread; memory-bound.
// ---------------------------------------------------------------------------
__global__ __launch_bounds__(256) void merge_kernel(
    const bf16* __restrict__ oc0, bf16* __restrict__ ob,
    const float2* __restrict__ ml)
{
  const int e8 = blockIdx.x * 256 + threadIdx.x;     // 0 .. 524287
  const size_t off = (size_t)e8 * 8;
  const int row = (int)(off >> 10);                  // b*CS + s
  const int col = (int)(off & 1023);
  const int h = col >> 6;
  const int b = row >> 11;
  const int s = row & (CS - 1);
  float2 ml0 = ml[(((size_t)0 * CB + b) * CH + h) * CS + s];
  float2 ml1 = ml[(((size_t)1 * CB + b) * CH + h) * CS + s];
  float M = fmaxf(ml0.x, ml1.x);
  float c0 = exp2f(ml0.x - M), c1 = exp2f(ml1.x - M);
  float inv = 1.0f / (c0 * ml0.y + c1 * ml1.y);
  ushort4 a0 = *(const ushort4*)((const unsigned short*)oc0 + off);
  ushort4 a1 = *(const ushort4*)((const unsigned short*)oc0 + off + 4);
  ushort4 b0 = *(const ushort4*)((const unsigned short*)ob + off);
  ushort4 b1 = *(const ushort4*)((const unsigned short*)ob + off + 4);
  unsigned short r[8];
  const unsigned short* p0 = &a0.x;
  const unsigned short* p1 = &b0.x;
  #pragma unroll
  for (int i = 0; i < 4; ++i)
    r[i] = f2bf((c0 * bf2f(p0[i]) + c1 * bf2f(p1[i])) * inv);
  p0 = &a1.x; p1 = &b1.x;
  #pragma unroll
  for (int i = 0; i < 4; ++i)
    r[4 + i] = f2bf((c0 * bf2f(p0[i]) + c1 * bf2f(p1[i])) * inv);
  *(ushort4*)((unsigned short*)ob + off) = make_ushort4(r[0], r[1], r[2], r[3]);
  *(ushort4*)((unsigned short*)ob + off + 4) = make_ushort4(r[4], r[5], r[6], r[7]);
}

// ---------------------------------------------------------------------------
extern "C" void kernel_launch(void* const* d_in, const int* in_sizes, int n_in,
                              void* d_out, int out_size, void* d_ws, size_t ws_size,
                              hipStream_t stream)
{
  const float* x  = (const float*)d_in[0];
  const float* wq = (const float*)d_in[1];
  const float* wk = (const float*)d_in[2];
  const float* wv = (const float*)d_in[3];
  const float* wo = (const float*)d_in[4];
  const float* fc = (const float*)d_in[5];
  const float* fs = (const float*)d_in[6];
  float* out = (float*)d_out;

  char* ws = (char*)d_ws;
  // workspace (peak ~34.6MB):
  //   [0, 8M):    x_b (dead after qkv GEMM) -> o_b (chunk1 partial + final)
  //   [8M, 11M):  wqkvt
  //   [11M, 13M): wot
  //   [13M, 21M): q_b
  //   [21M, 23M): k_b
  //   [23M, 25M): v_t
  //   [25M, 33M): oc0 (chunk0 partial)
  //   [33M, 34M): ml [2][B][H][S] float2
  bf16*   x_b   = (bf16*)(ws);
  bf16*   wqkvt = (bf16*)(ws + 8388608);
  bf16*   wot   = (bf16*)(ws + 11534336);
  bf16*   q_b   = (bf16*)(ws + 13631488);
  bf16*   k_b   = (bf16*)(ws + 22020096);
  bf16*   v_t   = (bf16*)(ws + 24117248);
  bf16*   o_b   = (bf16*)(ws);               // over x_b
  bf16*   oc0   = (bf16*)(ws + 26214400);
  float2* mlb   = (float2*)(ws + 34603008);

  prep_kernel<<<2688, 256, 0, stream>>>(x, x_b, wq, wk, wv, wo, wqkvt, wot);
  gemm_qkv_rope_kernel<<<dim3(32, 12), 256, 0, stream>>>(x_b, wqkvt, fc, fs, q_b, k_b, v_t);
  flash_split_kernel<<<1024, 256, 0, stream>>>(q_b, k_b, v_t, oc0, o_b, mlb);
  merge_kernel<<<2048, 256, 0, stream>>>(oc0, o_b, mlb);
  gemm_mfma_kernel<<<dim3(32, 8), 256, 0, stream>>>(o_b, wot, out, CM, CD, CNQ, CNQ);
}

// Round 16
// 126.107 us; speedup vs baseline: 2.8910x; 1.0242x over previous
//
#include <hip/hip_runtime.h>
#include <hip/hip_bf16.h>

using bf16 = __hip_bfloat16;
typedef short bf16x8 __attribute__((ext_vector_type(8)));
typedef float f32x4 __attribute__((ext_vector_type(4)));

#define CB 2
#define CS 2048
#define CD 1024
#define CH 16
#define CKH 4
#define CHD 64
#define CREP 4
#define CNQ (CH*CHD)    // 1024
#define CNKV (CKH*CHD)  // 256
#define CM (CB*CS)      // 4096

__device__ __forceinline__ unsigned short f2bf(float f) {
  union { float f; unsigned int i; } c; c.f = f;
  unsigned int r = c.i + 0x7FFFu + ((c.i >> 16) & 1u);  // RNE
  return (unsigned short)(r >> 16);
}
__device__ __forceinline__ float bf2f(unsigned short u) {
  union { unsigned int i; float f; } c;
  c.i = ((unsigned int)u) << 16;
  return c.f;
}
__device__ __forceinline__ void gload_lds16(const void* g, void* l) {
  __builtin_amdgcn_global_load_lds(
      (const __attribute__((address_space(1))) void*)g,
      (__attribute__((address_space(3))) void*)l, 16, 0, 0);
}

// ---------------------------------------------------------------------------
// bf16 MFMA GEMM v2 (R8-proven): C[M,N] f32 = A[M,K](lda) · Bt[N,K]^T.
// ---------------------------------------------------------------------------
__global__ __launch_bounds__(256) void gemm_mfma_kernel(
    const bf16* __restrict__ A, const bf16* __restrict__ Bt,
    float* __restrict__ C, int Mm, int Nn, int Kk, int lda)
{
  __shared__ __align__(16) bf16 As[2][128 * 32];
  __shared__ __align__(16) bf16 Bs[2][128 * 32];
  const int tid = threadIdx.x;
  const int lane = tid & 63;
  const int l15 = lane & 15;
  const int g = lane >> 4;
  const int wid = tid >> 6;
  const int wr = (wid >> 1) * 64;
  const int wc = (wid & 1) * 64;
  const int m0 = blockIdx.x * 128;
  const int n0 = blockIdx.y * 128;

  f32x4 acc[4][4];
  #pragma unroll
  for (int i = 0; i < 4; ++i)
    #pragma unroll
    for (int j = 0; j < 4; ++j)
      acc[i][j] = (f32x4){0.f, 0.f, 0.f, 0.f};

  const int sr = tid >> 2;
  const int sc = (tid & 3) * 8;
  const bf16* aSrc = A + (size_t)(m0 + sr) * lda + sc;
  const bf16* bSrc = Bt + (size_t)(n0 + sr) * Kk + sc;
  const int sOff = (tid & 192) * 8;

#define GSTAGE(bi, k0) do {                                             \
    gload_lds16(aSrc + (k0),                     &As[bi][sOff]);        \
    gload_lds16(aSrc + 64 * (size_t)lda + (k0),  &As[bi][sOff + 2048]); \
    gload_lds16(bSrc + (k0),                     &Bs[bi][sOff]);        \
    gload_lds16(bSrc + 64 * (size_t)Kk + (k0),   &Bs[bi][sOff + 2048]); \
  } while (0)

  const int nt = Kk >> 5;
  int bi = 0;
  GSTAGE(0, 0);
  for (int t = 0; t < nt; ++t) {
    if (t + 1 < nt) {
      GSTAGE(bi ^ 1, (t + 1) * 32);
      asm volatile("s_waitcnt vmcnt(4)" ::: "memory");
    } else {
      asm volatile("s_waitcnt vmcnt(0)" ::: "memory");
    }
    __builtin_amdgcn_s_barrier();
    asm volatile("" ::: "memory");

    bf16x8 af[4], bfr[4];
    #pragma unroll
    for (int mt = 0; mt < 4; ++mt)
      af[mt] = *(const bf16x8*)&As[bi][(wr + mt * 16 + l15) * 32 + g * 8];
    #pragma unroll
    for (int nt2 = 0; nt2 < 4; ++nt2)
      bfr[nt2] = *(const bf16x8*)&Bs[bi][(wc + nt2 * 16 + l15) * 32 + g * 8];
    #pragma unroll
    for (int mt = 0; mt < 4; ++mt)
      #pragma unroll
      for (int nt2 = 0; nt2 < 4; ++nt2)
        acc[mt][nt2] = __builtin_amdgcn_mfma_f32_16x16x32_bf16(af[mt], bfr[nt2], acc[mt][nt2], 0, 0, 0);

    asm volatile("" ::: "memory");
    __builtin_amdgcn_s_barrier();
    bi ^= 1;
  }
#undef GSTAGE

  #pragma unroll
  for (int mt = 0; mt < 4; ++mt)
    #pragma unroll
    for (int r4 = 0; r4 < 4; ++r4) {
      const size_t row = (size_t)(m0 + wr + mt * 16 + 4 * g + r4);
      #pragma unroll
      for (int nt2 = 0; nt2 < 4; ++nt2)
        C[row * Nn + n0 + wc + nt2 * 16 + l15] = acc[mt][nt2][r4];
    }
}

// ---------------------------------------------------------------------------
// qkv GEMM with fused RoPE + layout epilogue (R12-proven).
// R16 delta: q additionally scaled by 0.125*log2(e) so flash's softmax needs
// no per-score scale multiply.
// ---------------------------------------------------------------------------
__global__ __launch_bounds__(256) void gemm_qkv_rope_kernel(
    const bf16* __restrict__ A, const bf16* __restrict__ Bt,
    const float* __restrict__ fc, const float* __restrict__ fs,
    bf16* __restrict__ qb, bf16* __restrict__ kb, bf16* __restrict__ vt)
{
  __shared__ __align__(16) bf16 As[2][128 * 32];
  __shared__ __align__(16) bf16 Bs[2][128 * 32];
  const int tid = threadIdx.x;
  const int lane = tid & 63;
  const int l15 = lane & 15;
  const int g = lane >> 4;
  const int wid = tid >> 6;
  const int wr = (wid >> 1) * 64;
  const int wc = (wid & 1) * 64;
  const int m0 = blockIdx.x * 128;
  const int n0 = blockIdx.y * 128;
  const int Kk = CD;

  f32x4 acc[4][4];
  #pragma unroll
  for (int i = 0; i < 4; ++i)
    #pragma unroll
    for (int j = 0; j < 4; ++j)
      acc[i][j] = (f32x4){0.f, 0.f, 0.f, 0.f};

  const int sr = tid >> 2;
  const int sc = (tid & 3) * 8;
  const bf16* aSrc = A + (size_t)(m0 + sr) * Kk + sc;
  const bf16* bSrc = Bt + (size_t)(n0 + sr) * Kk + sc;
  const int sOff = (tid & 192) * 8;

#define GSTAGE(bi, k0) do {                                             \
    gload_lds16(aSrc + (k0),                     &As[bi][sOff]);        \
    gload_lds16(aSrc + 64 * (size_t)Kk + (k0),   &As[bi][sOff + 2048]); \
    gload_lds16(bSrc + (k0),                     &Bs[bi][sOff]);        \
    gload_lds16(bSrc + 64 * (size_t)Kk + (k0),   &Bs[bi][sOff + 2048]); \
  } while (0)

  const int nt = Kk >> 5;
  int bi = 0;
  GSTAGE(0, 0);
  for (int t = 0; t < nt; ++t) {
    if (t + 1 < nt) {
      GSTAGE(bi ^ 1, (t + 1) * 32);
      asm volatile("s_waitcnt vmcnt(4)" ::: "memory");
    } else {
      asm volatile("s_waitcnt vmcnt(0)" ::: "memory");
    }
    __builtin_amdgcn_s_barrier();
    asm volatile("" ::: "memory");

    bf16x8 af[4], bfr[4];
    #pragma unroll
    for (int mt = 0; mt < 4; ++mt)
      af[mt] = *(const bf16x8*)&As[bi][(wr + mt * 16 + l15) * 32 + g * 8];
    #pragma unroll
    for (int nt2 = 0; nt2 < 4; ++nt2)
      bfr[nt2] = *(const bf16x8*)&Bs[bi][(wc + nt2 * 16 + l15) * 32 + g * 8];
    #pragma unroll
    for (int mt = 0; mt < 4; ++mt)
      #pragma unroll
      for (int nt2 = 0; nt2 < 4; ++nt2)
        acc[mt][nt2] = __builtin_amdgcn_mfma_f32_16x16x32_bf16(af[mt], bfr[nt2], acc[mt][nt2], 0, 0, 0);

    asm volatile("" ::: "memory");
    __builtin_amdgcn_s_barrier();
    bi ^= 1;
  }
#undef GSTAGE

  if (blockIdx.y < 10) {
    const bool isq = (blockIdx.y < 8);
    const float qsc = isq ? 0.18033688f : 1.0f;   // 0.125*log2(e) folded into q
    #pragma unroll
    for (int mt = 0; mt < 4; ++mt)
      #pragma unroll
      for (int r4 = 0; r4 < 4; ++r4) {
        int m = m0 + wr + mt * 16 + 4 * g + r4;
        int s = m & (CS - 1), bb = m >> 11;
        #pragma unroll
        for (int nt2 = 0; nt2 < 4; ++nt2) {
          int n = n0 + wc + nt2 * 16 + l15;
          int d = n & 63;
          float val = acc[mt][nt2][r4];
          float par = __shfl_xor(val, 1, 64);
          float cv = fc[s * 32 + (d >> 1)];
          float sv = fs[s * 32 + (d >> 1)];
          float o = (d & 1) ? (par * sv + val * cv) : (val * cv - par * sv);
          o *= qsc;
          if (isq) {
            int h = n >> 6;
            ((unsigned short*)qb)[(((size_t)bb * CH + h) * CS + s) * CHD + d] = f2bf(o);
          } else {
            int kh = (n >> 6) - 16;
            ((unsigned short*)kb)[(((size_t)bb * CKH + kh) * CS + s) * CHD + d] = f2bf(o);
          }
        }
      }
  } else {
    #pragma unroll
    for (int mt = 0; mt < 4; ++mt) {
      int mb = m0 + wr + mt * 16 + 4 * g;
      int s0 = mb & (CS - 1), bb = mb >> 11;
      #pragma unroll
      for (int nt2 = 0; nt2 < 4; ++nt2) {
        int n = n0 + wc + nt2 * 16 + l15;
        int d = n & 63;
        int kh = (n >> 6) - 20;
        ushort4 pk = make_ushort4(f2bf(acc[mt][nt2][0]), f2bf(acc[mt][nt2][1]),
                                  f2bf(acc[mt][nt2][2]), f2bf(acc[mt][nt2][3]));
        *(ushort4*)&((unsigned short*)vt)[(((size_t)bb * CKH + kh) * CHD + d) * CS + s0] = pk;
      }
    }
  }
}

// ---------------------------------------------------------------------------
// Merged prep (R13-proven): conv_x (blocks 0..2047) + 4 weight transposes.
// ---------------------------------------------------------------------------
__global__ __launch_bounds__(256) void prep_kernel(
    const float* __restrict__ x, bf16* __restrict__ xb,
    const float* __restrict__ wq, const float* __restrict__ wk,
    const float* __restrict__ wv, const float* __restrict__ wo,
    bf16* __restrict__ wqkvt, bf16* __restrict__ wot)
{
  const int tid = threadIdx.x;
  int bid = blockIdx.x;
  if (bid < 2048) {
    int i = (bid * 256 + tid) * 8;
    float4 a = *(const float4*)&x[i];
    float4 b = *(const float4*)&x[i + 4];
    unsigned short* o = (unsigned short*)xb + i;
    *(ushort4*)o = make_ushort4(f2bf(a.x), f2bf(a.y), f2bf(a.z), f2bf(a.w));
    *(ushort4*)(o + 4) = make_ushort4(f2bf(b.x), f2bf(b.y), f2bf(b.z), f2bf(b.w));
    return;
  }
  bid -= 2048;
  const float* W; bf16* Wt; int Nn, bx, by;
  if (bid < 256)      { W = wq; Wt = wqkvt;                      Nn = 1024; bx = bid & 15;        by = bid >> 4; }
  else if (bid < 320) { W = wk; Wt = wqkvt + (size_t)1024 * CD;  Nn = 256;  bx = (bid-256) & 15;  by = (bid-256) >> 4; }
  else if (bid < 384) { W = wv; Wt = wqkvt + (size_t)1280 * CD;  Nn = 256;  bx = (bid-320) & 15;  by = (bid-320) >> 4; }
  else                { W = wo; Wt = wot;                        Nn = 1024; bx = (bid-384) & 15;  by = (bid-384) >> 4; }
  const int Kk = 1024;
  const int k0 = bx * 64;
  const int n0 = by * 64;

  __shared__ float T[64][65];
  const int lr = tid >> 4;
  const int lc = (tid & 15) * 4;
  #pragma unroll
  for (int i = 0; i < 4; ++i) {
    float4 v = *(const float4*)&W[(size_t)(k0 + lr + i * 16) * Nn + n0 + lc];
    T[lr + i * 16][lc + 0] = v.x;
    T[lr + i * 16][lc + 1] = v.y;
    T[lr + i * 16][lc + 2] = v.z;
    T[lr + i * 16][lc + 3] = v.w;
  }
  __syncthreads();
  const int rn = tid >> 3;
  const int ck = (tid & 7) * 8;
  #pragma unroll
  for (int i = 0; i < 2; ++i) {
    int nn = rn + i * 32;
    unsigned short u[8];
    #pragma unroll
    for (int e = 0; e < 8; ++e) u[e] = f2bf(T[ck + e][nn]);
    unsigned short* dst = (unsigned short*)Wt + (size_t)(n0 + nn) * Kk + k0 + ck;
    *(ushort4*)dst = make_ushort4(u[0], u[1], u[2], u[3]);
    *(ushort4*)(dst + 4) = make_ushort4(u[4], u[5], u[6], u[7]);
  }
}

// ---------------------------------------------------------------------------
// MFMA flash attention, cross-block split-KV x2 (R15-proven structure).
// R16 deltas (VALU-cut): (a) no per-score scale (Q pre-scaled in GEMM
// epilogue); (b) P packed by TRUNCATION pair-pack (3 VALU/pair vs ~8) —
// the downward bias cancels because l (ones-MFMA) uses the same truncated
// values as the PV numerator.
// ---------------------------------------------------------------------------
__global__ __launch_bounds__(256, 2) void flash_split_kernel(
    const bf16* __restrict__ qb, const bf16* __restrict__ kb,
    const bf16* __restrict__ vt, bf16* __restrict__ oc0,
    bf16* __restrict__ ob, float2* __restrict__ ml)
{
  __shared__ __align__(16) char arena[51200];
  char* KL = arena;                       // [2][8192]: K tile 64x(64 bf16)
  char* VL = arena + 16384;               // [2][8192]: V^T tile 64x(64 bf16)
  const int tid = threadIdx.x;
  const int lane = tid & 63;
  const int wid = tid >> 6;
  unsigned short* PLW = (unsigned short*)(arena + 32768) + wid * 2304; // [32][72]
  const int l15 = lane & 15;
  const int g = lane >> 4;
  const int blk = blockIdx.x;
  const int chunk = blk & 1;
  const int grp = (blk >> 1) & 7;         // b*4+kh
  const int idx = blk >> 4;               // 0..63
  const int qt = 63 - idx;                // longest pairs first
  const int kh = grp & 3;
  const int b = grp >> 2;
  const int h = kh * CREP + wid;
  const int N64 = (qt >> 1) + 1;
  const int hc = N64 >> 1;
  const int tbeg = chunk ? hc : 0;
  const int tend = chunk ? N64 : hc;

  const bf16* qbase = qb + ((size_t)(b * CH + h) * CS + qt * 32) * CHD;
  const bf16* kbase = kb + (size_t)(b * CKH + kh) * CS * CHD;
  const bf16* vbase = vt + (size_t)(b * CKH + kh) * CHD * CS;  // [d][s]

  bf16x8 qf[2][2];
  #pragma unroll
  for (int qs = 0; qs < 2; ++qs)
    #pragma unroll
    for (int c = 0; c < 2; ++c)
      qf[qs][c] = *(const bf16x8*)(qbase + (qs * 16 + l15) * CHD + c * 32 + g * 8);

  bf16x8 ones;
  #pragma unroll
  for (int e = 0; e < 8; ++e) ones[e] = (short)0x3F80;  // bf16 1.0

  f32x4 oacc[2][4];
  f32x4 lacc[2];
  #pragma unroll
  for (int qs = 0; qs < 2; ++qs) {
    lacc[qs] = (f32x4){0.f, 0.f, 0.f, 0.f};
    #pragma unroll
    for (int dt = 0; dt < 4; ++dt)
      oacc[qs][dt] = (f32x4){0.f, 0.f, 0.f, 0.f};
  }
  float mrow[2] = {-1e30f, -1e30f};

  const int slr = tid >> 3;
  const int scg = (tid & 7) ^ (slr & 7);
  const bf16* kstage = kbase + (size_t)slr * CHD + scg * 8;
  const bf16* vstage = vbase + (size_t)slr * CS + scg * 8;
  char* kdst = KL + wid * 1024;
  char* vdst = VL + wid * 1024;

#define STAGE(bi, t64) do {                                        \
    const bf16* ks_ = kstage + (size_t)(t64) * 64 * CHD;           \
    const bf16* vs_ = vstage + (t64) * 64;                         \
    gload_lds16(ks_,            kdst + (bi) * 8192);               \
    gload_lds16(ks_ + 32 * CHD, kdst + (bi) * 8192 + 4096);        \
    gload_lds16(vs_,            vdst + (bi) * 8192);               \
    gload_lds16(vs_ + 32 * CS,  vdst + (bi) * 8192 + 4096);        \
  } while (0)

  if (tbeg < tend) {
    int bi = 0;
    STAGE(0, tbeg);
    for (int t = tbeg; t < tend; ++t) {
      if (t + 1 < tend) {
        STAGE(bi ^ 1, t + 1);
        asm volatile("s_waitcnt vmcnt(4)" ::: "memory");
      } else {
        asm volatile("s_waitcnt vmcnt(0)" ::: "memory");
      }
      __builtin_amdgcn_s_barrier();
      asm volatile("" ::: "memory");

      const char* KB = KL + bi * 8192;
      const char* VB = VL + bi * 8192;
      bf16x8 kfr[4][2], vfr[4][2];
      #pragma unroll
      for (int kt = 0; kt < 4; ++kt) {
        int row = kt * 16 + l15;
        #pragma unroll
        for (int c = 0; c < 2; ++c)
          kfr[kt][c] = *(const bf16x8*)(KB + row * 128 + (((c * 4 + g) ^ (row & 7)) << 4));
      }
      #pragma unroll
      for (int dt = 0; dt < 4; ++dt) {
        int row = dt * 16 + l15;
        #pragma unroll
        for (int st = 0; st < 2; ++st)
          vfr[dt][st] = *(const bf16x8*)(VB + row * 128 + (((st * 4 + g) ^ (row & 7)) << 4));
      }

      // QK^T (swapped): S^T[k][q] — already in exp2 domain (Q pre-scaled)
      f32x4 sacc[4][2];
      #pragma unroll
      for (int kt = 0; kt < 4; ++kt)
        #pragma unroll
        for (int qs = 0; qs < 2; ++qs)
          sacc[kt][qs] = (f32x4){0.f, 0.f, 0.f, 0.f};
      #pragma unroll
      for (int c = 0; c < 2; ++c)
        #pragma unroll
        for (int kt = 0; kt < 4; ++kt)
          #pragma unroll
          for (int qs = 0; qs < 2; ++qs)
            sacc[kt][qs] = __builtin_amdgcn_mfma_f32_16x16x32_bf16(kfr[kt][c], qf[qs][c], sacc[kt][qs], 0, 0, 0);

      const bool diag = (t == N64 - 1);   // only reachable in chunk1
      #pragma unroll
      for (int qs = 0; qs < 2; ++qs) {
        float pe[16];
        float pm = -1e30f;
        #pragma unroll
        for (int kt = 0; kt < 4; ++kt)
          #pragma unroll
          for (int r = 0; r < 4; ++r) {
            float v = sacc[kt][qs][r];
            if (diag) {
              int koff = t * 64 + kt * 16 + 4 * g + r;
              if (koff > qt * 32 + qs * 16 + l15) v = -1e30f;
            }
            pe[kt * 4 + r] = v;
            pm = fmaxf(pm, v);
          }
        if (__any(pm > mrow[qs] + 8.0f)) {       // slow path: exact rescale
          pm = fmaxf(pm, __shfl_xor(pm, 16, 64));
          pm = fmaxf(pm, __shfl_xor(pm, 32, 64));
          float nm = fmaxf(mrow[qs], pm);
          float corr = exp2f(mrow[qs] - nm);
          mrow[qs] = nm;
          lacc[qs] *= corr;
          #pragma unroll
          for (int dt = 0; dt < 4; ++dt) oacc[qs][dt] *= corr;
        }
        #pragma unroll
        for (int i = 0; i < 16; ++i)
          pe[i] = exp2f(pe[i] - mrow[qs]);       // p <= 2^8
        // truncation pair-pack (bias cancels: l uses same truncated values)
        #pragma unroll
        for (int kt = 0; kt < 4; ++kt) {
          unsigned int lo = (__float_as_uint(pe[kt * 4 + 1]) & 0xFFFF0000u) |
                            (__float_as_uint(pe[kt * 4 + 0]) >> 16);
          unsigned int hi = (__float_as_uint(pe[kt * 4 + 3]) & 0xFFFF0000u) |
                            (__float_as_uint(pe[kt * 4 + 2]) >> 16);
          *(uint2*)&PLW[(qs * 16 + l15) * 72 + kt * 16 + 4 * g] = make_uint2(lo, hi);
        }
      }

      // PV + psum (same-wave LDS RAW)
      #pragma unroll
      for (int qs = 0; qs < 2; ++qs) {
        #pragma unroll
        for (int st = 0; st < 2; ++st) {
          bf16x8 pf = *(const bf16x8*)&PLW[(qs * 16 + l15) * 72 + st * 32 + g * 8];
          lacc[qs] = __builtin_amdgcn_mfma_f32_16x16x32_bf16(ones, pf, lacc[qs], 0, 0, 0);
          #pragma unroll
          for (int dt = 0; dt < 4; ++dt)
            oacc[qs][dt] = __builtin_amdgcn_mfma_f32_16x16x32_bf16(vfr[dt][st], pf, oacc[qs][dt], 0, 0, 0);
        }
      }

      asm volatile("" ::: "memory");
      __builtin_amdgcn_s_barrier();
      bi ^= 1;
    }
  }
#undef STAGE

  // partial write: unnormalized O (bf16) + (m,l). Kernel boundary = sync.
  unsigned short* pdst = (unsigned short*)(chunk ? ob : oc0);
  #pragma unroll
  for (int qs = 0; qs < 2; ++qs) {
    int qg = qt * 32 + qs * 16 + l15;
    unsigned short* prow = pdst + (size_t)(b * CS + qg) * CNQ + h * CHD;
    #pragma unroll
    for (int dt = 0; dt < 4; ++dt)
      *(ushort4*)&prow[dt * 16 + 4 * g] =
          make_ushort4(f2bf(oacc[qs][dt][0]), f2bf(oacc[qs][dt][1]),
                       f2bf(oacc[qs][dt][2]), f2bf(oacc[qs][dt][3]));
    if (g == 0)
      ml[(((size_t)chunk * CB + b) * CH + h) * CS + qg] = make_float2(mrow[qs], lacc[qs][0]);
  }
}

// ---------------------------------------------------------------------------
// Merge: final_o = (c0*o0 + c1*o1) / (c0*l0 + c1*l1), in-place over ob.
// ---------------------------------------------------------------------------
__global__ __launch_bounds__(256) void merge_kernel(
    const bf16* __restrict__ oc0, bf16* __restrict__ ob,
    const float2* __restrict__ ml)
{
  const int e8 = blockIdx.x * 256 + threadIdx.x;     // 0 .. 524287
  const size_t off = (size_t)e8 * 8;
  const int row = (int)(off >> 10);                  // b*CS + s
  const int col = (int)(off & 1023);
  const int h = col >> 6;
  const int b = row >> 11;
  const int s = row & (CS - 1);
  float2 ml0 = ml[(((size_t)0 * CB + b) * CH + h) * CS + s];
  float2 ml1 = ml[(((size_t)1 * CB + b) * CH + h) * CS + s];
  float M = fmaxf(ml0.x, ml1.x);
  float c0 = exp2f(ml0.x - M), c1 = exp2f(ml1.x - M);
  float inv = 1.0f / (c0 * ml0.y + c1 * ml1.y);
  ushort4 a0 = *(const ushort4*)((const unsigned short*)oc0 + off);
  ushort4 a1 = *(const ushort4*)((const unsigned short*)oc0 + off + 4);
  ushort4 b0 = *(const ushort4*)((const unsigned short*)ob + off);
  ushort4 b1 = *(const ushort4*)((const unsigned short*)ob + off + 4);
  unsigned short r[8];
  const unsigned short* p0 = &a0.x;
  const unsigned short* p1 = &b0.x;
  #pragma unroll
  for (int i = 0; i < 4; ++i)
    r[i] = f2bf((c0 * bf2f(p0[i]) + c1 * bf2f(p1[i])) * inv);
  p0 = &a1.x; p1 = &b1.x;
  #pragma unroll
  for (int i = 0; i < 4; ++i)
    r[4 + i] = f2bf((c0 * bf2f(p0[i]) + c1 * bf2f(p1[i])) * inv);
  *(ushort4*)((unsigned short*)ob + off) = make_ushort4(r[0], r[1], r[2], r[3]);
  *(ushort4*)((unsigned short*)ob + off + 4) = make_ushort4(r[4], r[5], r[6], r[7]);
}

// ---------------------------------------------------------------------------
extern "C" void kernel_launch(void* const* d_in, const int* in_sizes, int n_in,
                              void* d_out, int out_size, void* d_ws, size_t ws_size,
                              hipStream_t stream)
{
  const float* x  = (const float*)d_in[0];
  const float* wq = (const float*)d_in[1];
  const float* wk = (const float*)d_in[2];
  const float* wv = (const float*)d_in[3];
  const float* wo = (const float*)d_in[4];
  const float* fc = (const float*)d_in[5];
  const float* fs = (const float*)d_in[6];
  float* out = (float*)d_out;

  char* ws = (char*)d_ws;
  // workspace (peak ~34.6MB):
  bf16*   x_b   = (bf16*)(ws);
  bf16*   wqkvt = (bf16*)(ws + 8388608);
  bf16*   wot   = (bf16*)(ws + 11534336);
  bf16*   q_b   = (bf16*)(ws + 13631488);
  bf16*   k_b   = (bf16*)(ws + 22020096);
  bf16*   v_t   = (bf16*)(ws + 24117248);
  bf16*   o_b   = (bf16*)(ws);               // over x_b
  bf16*   oc0   = (bf16*)(ws + 26214400);
  float2* mlb   = (float2*)(ws + 34603008);

  prep_kernel<<<2688, 256, 0, stream>>>(x, x_b, wq, wk, wv, wo, wqkvt, wot);
  gemm_qkv_rope_kernel<<<dim3(32, 12), 256, 0, stream>>>(x_b, wqkvt, fc, fs, q_b, k_b, v_t);
  flash_split_kernel<<<1024, 256, 0, stream>>>(q_b, k_b, v_t, oc0, o_b, mlb);
  merge_kernel<<<2048, 256, 0, stream>>>(oc0, o_b, mlb);
  gemm_mfma_kernel<<<dim3(32, 8), 256, 0, stream>>>(o_b, wot, out, CM, CD, CNQ, CNQ);
}

// Round 17
// 115.366 us; speedup vs baseline: 3.1602x; 1.0931x over previous
//
#include <hip/hip_runtime.h>
#include <hip/hip_bf16.h>

using bf16 = __hip_bfloat16;
typedef short bf16x8 __attribute__((ext_vector_type(8)));
typedef float f32x4 __attribute__((ext_vector_type(4)));

#define CB 2
#define CS 2048
#define CD 1024
#define CH 16
#define CKH 4
#define CHD 64
#define CREP 4
#define CNQ (CH*CHD)    // 1024
#define CNKV (CKH*CHD)  // 256
#define CM (CB*CS)      // 4096

__device__ __forceinline__ unsigned short f2bf(float f) {
  union { float f; unsigned int i; } c; c.f = f;
  unsigned int r = c.i + 0x7FFFu + ((c.i >> 16) & 1u);  // RNE
  return (unsigned short)(r >> 16);
}
__device__ __forceinline__ float bf2f(unsigned short u) {
  union { unsigned int i; float f; } c;
  c.i = ((unsigned int)u) << 16;
  return c.f;
}
__device__ __forceinline__ void gload_lds16(const void* g, void* l) {
  __builtin_amdgcn_global_load_lds(
      (const __attribute__((address_space(1))) void*)g,
      (__attribute__((address_space(3))) void*)l, 16, 0, 0);
}

// ---------------------------------------------------------------------------
// bf16 MFMA GEMM v3: 64x128 tile (2x2 waves of 32x64), BK=32, dbuf LDS,
// counted vmcnt(3). Smaller tile -> 2x the blocks of v2: fixes the
// grid-starvation (o-proj was 1 block/CU, qkv 1.5) while keeping the proven
// staging discipline. 8 MFMA : 6 ds_read per wave K-step. LDS 24KB.
// ---------------------------------------------------------------------------
__global__ __launch_bounds__(256) void gemm_mfma_kernel(
    const bf16* __restrict__ A, const bf16* __restrict__ Bt,
    float* __restrict__ C, int Mm, int Nn, int Kk, int lda)
{
  __shared__ __align__(16) bf16 As[2][64 * 32];
  __shared__ __align__(16) bf16 Bs[2][128 * 32];
  const int tid = threadIdx.x;
  const int lane = tid & 63;
  const int l15 = lane & 15;
  const int g = lane >> 4;
  const int wid = tid >> 6;
  const int wr = (wid >> 1) * 32;
  const int wc = (wid & 1) * 64;
  const int m0 = blockIdx.x * 64;
  const int n0 = blockIdx.y * 128;

  f32x4 acc[2][4];
  #pragma unroll
  for (int i = 0; i < 2; ++i)
    #pragma unroll
    for (int j = 0; j < 4; ++j)
      acc[i][j] = (f32x4){0.f, 0.f, 0.f, 0.f};

  const int sr = tid >> 2;            // 0..63
  const int sc = (tid & 3) * 8;
  const bf16* aSrc = A + (size_t)(m0 + sr) * lda + sc;
  const bf16* bSrc = Bt + (size_t)(n0 + sr) * Kk + sc;
  const int sOff = (tid & 192) * 8;   // wave-uniform linear LDS base (elems)

#define GSTAGE(bi, k0) do {                                             \
    gload_lds16(aSrc + (k0),                     &As[bi][sOff]);        \
    gload_lds16(bSrc + (k0),                     &Bs[bi][sOff]);        \
    gload_lds16(bSrc + 64 * (size_t)Kk + (k0),   &Bs[bi][sOff + 2048]); \
  } while (0)

  const int nt = Kk >> 5;
  int bi = 0;
  GSTAGE(0, 0);
  for (int t = 0; t < nt; ++t) {
    if (t + 1 < nt) {
      GSTAGE(bi ^ 1, (t + 1) * 32);
      asm volatile("s_waitcnt vmcnt(3)" ::: "memory");   // tile-t loads done
    } else {
      asm volatile("s_waitcnt vmcnt(0)" ::: "memory");
    }
    __builtin_amdgcn_s_barrier();
    asm volatile("" ::: "memory");

    bf16x8 af[2], bfr[4];
    #pragma unroll
    for (int mt = 0; mt < 2; ++mt)
      af[mt] = *(const bf16x8*)&As[bi][(wr + mt * 16 + l15) * 32 + g * 8];
    #pragma unroll
    for (int nt2 = 0; nt2 < 4; ++nt2)
      bfr[nt2] = *(const bf16x8*)&Bs[bi][(wc + nt2 * 16 + l15) * 32 + g * 8];
    #pragma unroll
    for (int mt = 0; mt < 2; ++mt)
      #pragma unroll
      for (int nt2 = 0; nt2 < 4; ++nt2)
        acc[mt][nt2] = __builtin_amdgcn_mfma_f32_16x16x32_bf16(af[mt], bfr[nt2], acc[mt][nt2], 0, 0, 0);

    asm volatile("" ::: "memory");
    __builtin_amdgcn_s_barrier();
    bi ^= 1;
  }
#undef GSTAGE

  #pragma unroll
  for (int mt = 0; mt < 2; ++mt)
    #pragma unroll
    for (int r4 = 0; r4 < 4; ++r4) {
      const size_t row = (size_t)(m0 + wr + mt * 16 + 4 * g + r4);
      #pragma unroll
      for (int nt2 = 0; nt2 < 4; ++nt2)
        C[row * Nn + n0 + wc + nt2 * 16 + l15] = acc[mt][nt2][r4];
    }
}

// ---------------------------------------------------------------------------
// qkv GEMM with fused RoPE + layout epilogue, 64x128 tile version.
// Grid (64, 12): blockIdx.y regions 0..7=q, 8..9=k, 10..11=v (n0 = y*128).
// q pre-scaled by 0.125*log2(e) (R16).
// ---------------------------------------------------------------------------
__global__ __launch_bounds__(256) void gemm_qkv_rope_kernel(
    const bf16* __restrict__ A, const bf16* __restrict__ Bt,
    const float* __restrict__ fc, const float* __restrict__ fs,
    bf16* __restrict__ qb, bf16* __restrict__ kb, bf16* __restrict__ vt)
{
  __shared__ __align__(16) bf16 As[2][64 * 32];
  __shared__ __align__(16) bf16 Bs[2][128 * 32];
  const int tid = threadIdx.x;
  const int lane = tid & 63;
  const int l15 = lane & 15;
  const int g = lane >> 4;
  const int wid = tid >> 6;
  const int wr = (wid >> 1) * 32;
  const int wc = (wid & 1) * 64;
  const int m0 = blockIdx.x * 64;
  const int n0 = blockIdx.y * 128;
  const int Kk = CD;

  f32x4 acc[2][4];
  #pragma unroll
  for (int i = 0; i < 2; ++i)
    #pragma unroll
    for (int j = 0; j < 4; ++j)
      acc[i][j] = (f32x4){0.f, 0.f, 0.f, 0.f};

  const int sr = tid >> 2;
  const int sc = (tid & 3) * 8;
  const bf16* aSrc = A + (size_t)(m0 + sr) * Kk + sc;
  const bf16* bSrc = Bt + (size_t)(n0 + sr) * Kk + sc;
  const int sOff = (tid & 192) * 8;

#define GSTAGE(bi, k0) do {                                             \
    gload_lds16(aSrc + (k0),                     &As[bi][sOff]);        \
    gload_lds16(bSrc + (k0),                     &Bs[bi][sOff]);        \
    gload_lds16(bSrc + 64 * (size_t)Kk + (k0),   &Bs[bi][sOff + 2048]); \
  } while (0)

  const int nt = Kk >> 5;
  int bi = 0;
  GSTAGE(0, 0);
  for (int t = 0; t < nt; ++t) {
    if (t + 1 < nt) {
      GSTAGE(bi ^ 1, (t + 1) * 32);
      asm volatile("s_waitcnt vmcnt(3)" ::: "memory");
    } else {
      asm volatile("s_waitcnt vmcnt(0)" ::: "memory");
    }
    __builtin_amdgcn_s_barrier();
    asm volatile("" ::: "memory");

    bf16x8 af[2], bfr[4];
    #pragma unroll
    for (int mt = 0; mt < 2; ++mt)
      af[mt] = *(const bf16x8*)&As[bi][(wr + mt * 16 + l15) * 32 + g * 8];
    #pragma unroll
    for (int nt2 = 0; nt2 < 4; ++nt2)
      bfr[nt2] = *(const bf16x8*)&Bs[bi][(wc + nt2 * 16 + l15) * 32 + g * 8];
    #pragma unroll
    for (int mt = 0; mt < 2; ++mt)
      #pragma unroll
      for (int nt2 = 0; nt2 < 4; ++nt2)
        acc[mt][nt2] = __builtin_amdgcn_mfma_f32_16x16x32_bf16(af[mt], bfr[nt2], acc[mt][nt2], 0, 0, 0);

    asm volatile("" ::: "memory");
    __builtin_amdgcn_s_barrier();
    bi ^= 1;
  }
#undef GSTAGE

  if (blockIdx.y < 10) {
    const bool isq = (blockIdx.y < 8);
    const float qsc = isq ? 0.18033688f : 1.0f;   // 0.125*log2(e) folded into q
    #pragma unroll
    for (int mt = 0; mt < 2; ++mt)
      #pragma unroll
      for (int r4 = 0; r4 < 4; ++r4) {
        int m = m0 + wr + mt * 16 + 4 * g + r4;
        int s = m & (CS - 1), bb = m >> 11;
        #pragma unroll
        for (int nt2 = 0; nt2 < 4; ++nt2) {
          int n = n0 + wc + nt2 * 16 + l15;
          int d = n & 63;
          float val = acc[mt][nt2][r4];
          float par = __shfl_xor(val, 1, 64);
          float cv = fc[s * 32 + (d >> 1)];
          float sv = fs[s * 32 + (d >> 1)];
          float o = (d & 1) ? (par * sv + val * cv) : (val * cv - par * sv);
          o *= qsc;
          if (isq) {
            int h = n >> 6;
            ((unsigned short*)qb)[(((size_t)bb * CH + h) * CS + s) * CHD + d] = f2bf(o);
          } else {
            int kh = (n >> 6) - 16;
            ((unsigned short*)kb)[(((size_t)bb * CKH + kh) * CS + s) * CHD + d] = f2bf(o);
          }
        }
      }
  } else {
    #pragma unroll
    for (int mt = 0; mt < 2; ++mt) {
      int mb = m0 + wr + mt * 16 + 4 * g;
      int s0 = mb & (CS - 1), bb = mb >> 11;
      #pragma unroll
      for (int nt2 = 0; nt2 < 4; ++nt2) {
        int n = n0 + wc + nt2 * 16 + l15;
        int d = n & 63;
        int kh = (n >> 6) - 20;
        ushort4 pk = make_ushort4(f2bf(acc[mt][nt2][0]), f2bf(acc[mt][nt2][1]),
                                  f2bf(acc[mt][nt2][2]), f2bf(acc[mt][nt2][3]));
        *(ushort4*)&((unsigned short*)vt)[(((size_t)bb * CKH + kh) * CHD + d) * CS + s0] = pk;
      }
    }
  }
}

// ---------------------------------------------------------------------------
// Merged prep (R13-proven): conv_x (blocks 0..2047) + 4 weight transposes.
// ---------------------------------------------------------------------------
__global__ __launch_bounds__(256) void prep_kernel(
    const float* __restrict__ x, bf16* __restrict__ xb,
    const float* __restrict__ wq, const float* __restrict__ wk,
    const float* __restrict__ wv, const float* __restrict__ wo,
    bf16* __restrict__ wqkvt, bf16* __restrict__ wot)
{
  const int tid = threadIdx.x;
  int bid = blockIdx.x;
  if (bid < 2048) {
    int i = (bid * 256 + tid) * 8;
    float4 a = *(const float4*)&x[i];
    float4 b = *(const float4*)&x[i + 4];
    unsigned short* o = (unsigned short*)xb + i;
    *(ushort4*)o = make_ushort4(f2bf(a.x), f2bf(a.y), f2bf(a.z), f2bf(a.w));
    *(ushort4*)(o + 4) = make_ushort4(f2bf(b.x), f2bf(b.y), f2bf(b.z), f2bf(b.w));
    return;
  }
  bid -= 2048;
  const float* W; bf16* Wt; int Nn, bx, by;
  if (bid < 256)      { W = wq; Wt = wqkvt;                      Nn = 1024; bx = bid & 15;        by = bid >> 4; }
  else if (bid < 320) { W = wk; Wt = wqkvt + (size_t)1024 * CD;  Nn = 256;  bx = (bid-256) & 15;  by = (bid-256) >> 4; }
  else if (bid < 384) { W = wv; Wt = wqkvt + (size_t)1280 * CD;  Nn = 256;  bx = (bid-320) & 15;  by = (bid-320) >> 4; }
  else                { W = wo; Wt = wot;                        Nn = 1024; bx = (bid-384) & 15;  by = (bid-384) >> 4; }
  const int Kk = 1024;
  const int k0 = bx * 64;
  const int n0 = by * 64;

  __shared__ float T[64][65];
  const int lr = tid >> 4;
  const int lc = (tid & 15) * 4;
  #pragma unroll
  for (int i = 0; i < 4; ++i) {
    float4 v = *(const float4*)&W[(size_t)(k0 + lr + i * 16) * Nn + n0 + lc];
    T[lr + i * 16][lc + 0] = v.x;
    T[lr + i * 16][lc + 1] = v.y;
    T[lr + i * 16][lc + 2] = v.z;
    T[lr + i * 16][lc + 3] = v.w;
  }
  __syncthreads();
  const int rn = tid >> 3;
  const int ck = (tid & 7) * 8;
  #pragma unroll
  for (int i = 0; i < 2; ++i) {
    int nn = rn + i * 32;
    unsigned short u[8];
    #pragma unroll
    for (int e = 0; e < 8; ++e) u[e] = f2bf(T[ck + e][nn]);
    unsigned short* dst = (unsigned short*)Wt + (size_t)(n0 + nn) * Kk + k0 + ck;
    *(ushort4*)dst = make_ushort4(u[0], u[1], u[2], u[3]);
    *(ushort4*)(dst + 4) = make_ushort4(u[4], u[5], u[6], u[7]);
  }
}

// ---------------------------------------------------------------------------
// MFMA flash attention, cross-block split-KV x2 (R16-proven).
// ---------------------------------------------------------------------------
__global__ __launch_bounds__(256, 2) void flash_split_kernel(
    const bf16* __restrict__ qb, const bf16* __restrict__ kb,
    const bf16* __restrict__ vt, bf16* __restrict__ oc0,
    bf16* __restrict__ ob, float2* __restrict__ ml)
{
  __shared__ __align__(16) char arena[51200];
  char* KL = arena;                       // [2][8192]: K tile 64x(64 bf16)
  char* VL = arena + 16384;               // [2][8192]: V^T tile 64x(64 bf16)
  const int tid = threadIdx.x;
  const int lane = tid & 63;
  const int wid = tid >> 6;
  unsigned short* PLW = (unsigned short*)(arena + 32768) + wid * 2304; // [32][72]
  const int l15 = lane & 15;
  const int g = lane >> 4;
  const int blk = blockIdx.x;
  const int chunk = blk & 1;
  const int grp = (blk >> 1) & 7;         // b*4+kh
  const int idx = blk >> 4;               // 0..63
  const int qt = 63 - idx;                // longest pairs first
  const int kh = grp & 3;
  const int b = grp >> 2;
  const int h = kh * CREP + wid;
  const int N64 = (qt >> 1) + 1;
  const int hc = N64 >> 1;
  const int tbeg = chunk ? hc : 0;
  const int tend = chunk ? N64 : hc;

  const bf16* qbase = qb + ((size_t)(b * CH + h) * CS + qt * 32) * CHD;
  const bf16* kbase = kb + (size_t)(b * CKH + kh) * CS * CHD;
  const bf16* vbase = vt + (size_t)(b * CKH + kh) * CHD * CS;  // [d][s]

  bf16x8 qf[2][2];
  #pragma unroll
  for (int qs = 0; qs < 2; ++qs)
    #pragma unroll
    for (int c = 0; c < 2; ++c)
      qf[qs][c] = *(const bf16x8*)(qbase + (qs * 16 + l15) * CHD + c * 32 + g * 8);

  bf16x8 ones;
  #pragma unroll
  for (int e = 0; e < 8; ++e) ones[e] = (short)0x3F80;  // bf16 1.0

  f32x4 oacc[2][4];
  f32x4 lacc[2];
  #pragma unroll
  for (int qs = 0; qs < 2; ++qs) {
    lacc[qs] = (f32x4){0.f, 0.f, 0.f, 0.f};
    #pragma unroll
    for (int dt = 0; dt < 4; ++dt)
      oacc[qs][dt] = (f32x4){0.f, 0.f, 0.f, 0.f};
  }
  float mrow[2] = {-1e30f, -1e30f};

  const int slr = tid >> 3;
  const int scg = (tid & 7) ^ (slr & 7);
  const bf16* kstage = kbase + (size_t)slr * CHD + scg * 8;
  const bf16* vstage = vbase + (size_t)slr * CS + scg * 8;
  char* kdst = KL + wid * 1024;
  char* vdst = VL + wid * 1024;

#define STAGE(bi, t64) do {                                        \
    const bf16* ks_ = kstage + (size_t)(t64) * 64 * CHD;           \
    const bf16* vs_ = vstage + (t64) * 64;                         \
    gload_lds16(ks_,            kdst + (bi) * 8192);               \
    gload_lds16(ks_ + 32 * CHD, kdst + (bi) * 8192 + 4096);        \
    gload_lds16(vs_,            vdst + (bi) * 8192);               \
    gload_lds16(vs_ + 32 * CS,  vdst + (bi) * 8192 + 4096);        \
  } while (0)

  if (tbeg < tend) {
    int bi = 0;
    STAGE(0, tbeg);
    for (int t = tbeg; t < tend; ++t) {
      if (t + 1 < tend) {
        STAGE(bi ^ 1, t + 1);
        asm volatile("s_waitcnt vmcnt(4)" ::: "memory");
      } else {
        asm volatile("s_waitcnt vmcnt(0)" ::: "memory");
      }
      __builtin_amdgcn_s_barrier();
      asm volatile("" ::: "memory");

      const char* KB = KL + bi * 8192;
      const char* VB = VL + bi * 8192;
      bf16x8 kfr[4][2], vfr[4][2];
      #pragma unroll
      for (int kt = 0; kt < 4; ++kt) {
        int row = kt * 16 + l15;
        #pragma unroll
        for (int c = 0; c < 2; ++c)
          kfr[kt][c] = *(const bf16x8*)(KB + row * 128 + (((c * 4 + g) ^ (row & 7)) << 4));
      }
      #pragma unroll
      for (int dt = 0; dt < 4; ++dt) {
        int row = dt * 16 + l15;
        #pragma unroll
        for (int st = 0; st < 2; ++st)
          vfr[dt][st] = *(const bf16x8*)(VB + row * 128 + (((st * 4 + g) ^ (row & 7)) << 4));
      }

      // QK^T (swapped): S^T[k][q] — already in exp2 domain (Q pre-scaled)
      f32x4 sacc[4][2];
      #pragma unroll
      for (int kt = 0; kt < 4; ++kt)
        #pragma unroll
        for (int qs = 0; qs < 2; ++qs)
          sacc[kt][qs] = (f32x4){0.f, 0.f, 0.f, 0.f};
      #pragma unroll
      for (int c = 0; c < 2; ++c)
        #pragma unroll
        for (int kt = 0; kt < 4; ++kt)
          #pragma unroll
          for (int qs = 0; qs < 2; ++qs)
            sacc[kt][qs] = __builtin_amdgcn_mfma_f32_16x16x32_bf16(kfr[kt][c], qf[qs][c], sacc[kt][qs], 0, 0, 0);

      const bool diag = (t == N64 - 1);   // only reachable in chunk1
      #pragma unroll
      for (int qs = 0; qs < 2; ++qs) {
        float pe[16];
        float pm = -1e30f;
        #pragma unroll
        for (int kt = 0; kt < 4; ++kt)
          #pragma unroll
          for (int r = 0; r < 4; ++r) {
            float v = sacc[kt][qs][r];
            if (diag) {
              int koff = t * 64 + kt * 16 + 4 * g + r;
              if (koff > qt * 32 + qs * 16 + l15) v = -1e30f;
            }
            pe[kt * 4 + r] = v;
            pm = fmaxf(pm, v);
          }
        if (__any(pm > mrow[qs] + 8.0f)) {       // slow path: exact rescale
          pm = fmaxf(pm, __shfl_xor(pm, 16, 64));
          pm = fmaxf(pm, __shfl_xor(pm, 32, 64));
          float nm = fmaxf(mrow[qs], pm);
          float corr = exp2f(mrow[qs] - nm);
          mrow[qs] = nm;
          lacc[qs] *= corr;
          #pragma unroll
          for (int dt = 0; dt < 4; ++dt) oacc[qs][dt] *= corr;
        }
        #pragma unroll
        for (int i = 0; i < 16; ++i)
          pe[i] = exp2f(pe[i] - mrow[qs]);       // p <= 2^8
        // truncation pair-pack (bias cancels: l uses same truncated values)
        #pragma unroll
        for (int kt = 0; kt < 4; ++kt) {
          unsigned int lo = (__float_as_uint(pe[kt * 4 + 1]) & 0xFFFF0000u) |
                            (__float_as_uint(pe[kt * 4 + 0]) >> 16);
          unsigned int hi = (__float_as_uint(pe[kt * 4 + 3]) & 0xFFFF0000u) |
                            (__float_as_uint(pe[kt * 4 + 2]) >> 16);
          *(uint2*)&PLW[(qs * 16 + l15) * 72 + kt * 16 + 4 * g] = make_uint2(lo, hi);
        }
      }

      // PV + psum (same-wave LDS RAW)
      #pragma unroll
      for (int qs = 0; qs < 2; ++qs) {
        #pragma unroll
        for (int st = 0; st < 2; ++st) {
          bf16x8 pf = *(const bf16x8*)&PLW[(qs * 16 + l15) * 72 + st * 32 + g * 8];
          lacc[qs] = __builtin_amdgcn_mfma_f32_16x16x32_bf16(ones, pf, lacc[qs], 0, 0, 0);
          #pragma unroll
          for (int dt = 0; dt < 4; ++dt)
            oacc[qs][dt] = __builtin_amdgcn_mfma_f32_16x16x32_bf16(vfr[dt][st], pf, oacc[qs][dt], 0, 0, 0);
        }
      }

      asm volatile("" ::: "memory");
      __builtin_amdgcn_s_barrier();
      bi ^= 1;
    }
  }
#undef STAGE

  // partial write: unnormalized O (bf16) + (m,l). Kernel boundary = sync.
  unsigned short* pdst = (unsigned short*)(chunk ? ob : oc0);
  #pragma unroll
  for (int qs = 0; qs < 2; ++qs) {
    int qg = qt * 32 + qs * 16 + l15;
    unsigned short* prow = pdst + (size_t)(b * CS + qg) * CNQ + h * CHD;
    #pragma unroll
    for (int dt = 0; dt < 4; ++dt)
      *(ushort4*)&prow[dt * 16 + 4 * g] =
          make_ushort4(f2bf(oacc[qs][dt][0]), f2bf(oacc[qs][dt][1]),
                       f2bf(oacc[qs][dt][2]), f2bf(oacc[qs][dt][3]));
    if (g == 0)
      ml[(((size_t)chunk * CB + b) * CH + h) * CS + qg] = make_float2(mrow[qs], lacc[qs][0]);
  }
}

// ---------------------------------------------------------------------------
// Merge: final_o = (c0*o0 + c1*o1) / (c0*l0 + c1*l1), in-place over ob.
// ---------------------------------------------------------------------------
__global__ __launch_bounds__(256) void merge_kernel(
    const bf16* __restrict__ oc0, bf16* __restrict__ ob,
    const float2* __restrict__ ml)
{
  const int e8 = blockIdx.x * 256 + threadIdx.x;     // 0 .. 524287
  const size_t off = (size_t)e8 * 8;
  const int row = (int)(off >> 10);                  // b*CS + s
  const int col = (int)(off & 1023);
  const int h = col >> 6;
  const int b = row >> 11;
  const int s = row & (CS - 1);
  float2 ml0 = ml[(((size_t)0 * CB + b) * CH + h) * CS + s];
  float2 ml1 = ml[(((size_t)1 * CB + b) * CH + h) * CS + s];
  float M = fmaxf(ml0.x, ml1.x);
  float c0 = exp2f(ml0.x - M), c1 = exp2f(ml1.x - M);
  float inv = 1.0f / (c0 * ml0.y + c1 * ml1.y);
  ushort4 a0 = *(const ushort4*)((const unsigned short*)oc0 + off);
  ushort4 a1 = *(const ushort4*)((const unsigned short*)oc0 + off + 4);
  ushort4 b0 = *(const ushort4*)((const unsigned short*)ob + off);
  ushort4 b1 = *(const ushort4*)((const unsigned short*)ob + off + 4);
  unsigned short r[8];
  const unsigned short* p0 = &a0.x;
  const unsigned short* p1 = &b0.x;
  #pragma unroll
  for (int i = 0; i < 4; ++i)
    r[i] = f2bf((c0 * bf2f(p0[i]) + c1 * bf2f(p1[i])) * inv);
  p0 = &a1.x; p1 = &b1.x;
  #pragma unroll
  for (int i = 0; i < 4; ++i)
    r[4 + i] = f2bf((c0 * bf2f(p0[i]) + c1 * bf2f(p1[i])) * inv);
  *(ushort4*)((unsigned short*)ob + off) = make_ushort4(r[0], r[1], r[2], r[3]);
  *(ushort4*)((unsigned short*)ob + off + 4) = make_ushort4(r[4], r[5], r[6], r[7]);
}

// ---------------------------------------------------------------------------
extern "C" void kernel_launch(void* const* d_in, const int* in_sizes, int n_in,
                              void* d_out, int out_size, void* d_ws, size_t ws_size,
                              hipStream_t stream)
{
  const float* x  = (const float*)d_in[0];
  const float* wq = (const float*)d_in[1];
  const float* wk = (const float*)d_in[2];
  const float* wv = (const float*)d_in[3];
  const float* wo = (const float*)d_in[4];
  const float* fc = (const float*)d_in[5];
  const float* fs = (const float*)d_in[6];
  float* out = (float*)d_out;

  char* ws = (char*)d_ws;
  // workspace (peak ~34.6MB):
  bf16*   x_b   = (bf16*)(ws);
  bf16*   wqkvt = (bf16*)(ws + 8388608);
  bf16*   wot   = (bf16*)(ws + 11534336);
  bf16*   q_b   = (bf16*)(ws + 13631488);
  bf16*   k_b   = (bf16*)(ws + 22020096);
  bf16*   v_t   = (bf16*)(ws + 24117248);
  bf16*   o_b   = (bf16*)(ws);               // over x_b
  bf16*   oc0   = (bf16*)(ws + 26214400);
  float2* mlb   = (float2*)(ws + 34603008);

  prep_kernel<<<2688, 256, 0, stream>>>(x, x_b, wq, wk, wv, wo, wqkvt, wot);
  gemm_qkv_rope_kernel<<<dim3(64, 12), 256, 0, stream>>>(x_b, wqkvt, fc, fs, q_b, k_b, v_t);
  flash_split_kernel<<<1024, 256, 0, stream>>>(q_b, k_b, v_t, oc0, o_b, mlb);
  merge_kernel<<<2048, 256, 0, stream>>>(oc0, o_b, mlb);
  gemm_mfma_kernel<<<dim3(64, 8), 256, 0, stream>>>(o_b, wot, out, CM, CD, CNQ, CNQ);
}

// Round 18
// 106.038 us; speedup vs baseline: 3.4381x; 1.0880x over previous
//
#include <hip/hip_runtime.h>
#include <hip/hip_bf16.h>

using bf16 = __hip_bfloat16;
typedef short bf16x8 __attribute__((ext_vector_type(8)));
typedef float f32x4 __attribute__((ext_vector_type(4)));

#define CB 2
#define CS 2048
#define CD 1024
#define CH 16
#define CKH 4
#define CHD 64
#define CREP 4
#define CNQ (CH*CHD)    // 1024
#define CNKV (CKH*CHD)  // 256
#define CM (CB*CS)      // 4096

__device__ __forceinline__ unsigned short f2bf(float f) {
  union { float f; unsigned int i; } c; c.f = f;
  unsigned int r = c.i + 0x7FFFu + ((c.i >> 16) & 1u);  // RNE
  return (unsigned short)(r >> 16);
}
__device__ __forceinline__ float bf2f(unsigned short u) {
  union { unsigned int i; float f; } c;
  c.i = ((unsigned int)u) << 16;
  return c.f;
}
__device__ __forceinline__ void gload_lds16(const void* g, void* l) {
  __builtin_amdgcn_global_load_lds(
      (const __attribute__((address_space(1))) void*)g,
      (__attribute__((address_space(3))) void*)l, 16, 0, 0);
}

// ---------------------------------------------------------------------------
// bf16 MFMA GEMM v4: 64x128 tile, BK=64, flash-style XOR-swizzled LDS
// (64x64 sub-tiles, 128B rows; staging thread (row=tid>>3, chunk^(row&7))
// pre-swizzled source — the exact layout flash has run since R6).
// 2 barriers per 64-K step (half of v3), 16 MFMA : 12 ds_read per wave-step.
// LDS 48KB -> 3 blocks/CU.
// ---------------------------------------------------------------------------
__global__ __launch_bounds__(256) void gemm_mfma_kernel(
    const bf16* __restrict__ A, const bf16* __restrict__ Bt,
    float* __restrict__ C, int Mm, int Nn, int Kk, int lda)
{
  __shared__ __align__(16) bf16 As[2][64 * 64];
  __shared__ __align__(16) bf16 Bs[2][128 * 64];
  const int tid = threadIdx.x;
  const int lane = tid & 63;
  const int l15 = lane & 15;
  const int g = lane >> 4;
  const int wid = tid >> 6;
  const int wr = (wid >> 1) * 32;
  const int wc = (wid & 1) * 64;
  const int m0 = blockIdx.x * 64;
  const int n0 = blockIdx.y * 128;

  f32x4 acc[2][4];
  #pragma unroll
  for (int i = 0; i < 2; ++i)
    #pragma unroll
    for (int j = 0; j < 4; ++j)
      acc[i][j] = (f32x4){0.f, 0.f, 0.f, 0.f};

  // staging: thread -> row tid>>3 (0..31 per gload), pre-swizzled chunk
  const int slr = tid >> 3;
  const int scg = (tid & 7) ^ (slr & 7);
  const bf16* aStage = A + (size_t)(m0 + slr) * lda + scg * 8;
  const bf16* bStage = Bt + (size_t)(n0 + slr) * Kk + scg * 8;
  char* aDst = (char*)As + wid * 1024;   // wave-uniform base (+lane*16 by HW)
  char* bDst = (char*)Bs + wid * 1024;

#define GSTAGE(bi, k0) do {                                                   \
    gload_lds16(aStage + (k0),                      aDst + (bi) * 8192);      \
    gload_lds16(aStage + 32 * (size_t)lda + (k0),   aDst + (bi) * 8192 + 4096); \
    gload_lds16(bStage + (k0),                      bDst + (bi) * 16384);     \
    gload_lds16(bStage + 32 * (size_t)Kk + (k0),    bDst + (bi) * 16384 + 4096); \
    gload_lds16(bStage + 64 * (size_t)Kk + (k0),    bDst + (bi) * 16384 + 8192); \
    gload_lds16(bStage + 96 * (size_t)Kk + (k0),    bDst + (bi) * 16384 + 12288); \
  } while (0)

  const int nt = Kk >> 6;
  int bi = 0;
  GSTAGE(0, 0);
  for (int t = 0; t < nt; ++t) {
    if (t + 1 < nt) {
      GSTAGE(bi ^ 1, (t + 1) * 64);
      asm volatile("s_waitcnt vmcnt(6)" ::: "memory");   // tile-t loads done
    } else {
      asm volatile("s_waitcnt vmcnt(0)" ::: "memory");
    }
    __builtin_amdgcn_s_barrier();
    asm volatile("" ::: "memory");

    const char* AB = (const char*)As + bi * 8192;
    const char* BB = (const char*)Bs + bi * 16384;
    bf16x8 af[2][2], bfr[4][2];
    #pragma unroll
    for (int mt = 0; mt < 2; ++mt) {
      int row = wr + mt * 16 + l15;
      #pragma unroll
      for (int c = 0; c < 2; ++c)
        af[mt][c] = *(const bf16x8*)(AB + row * 128 + (((c * 4 + g) ^ (row & 7)) << 4));
    }
    #pragma unroll
    for (int nt2 = 0; nt2 < 4; ++nt2) {
      int row = wc + nt2 * 16 + l15;
      #pragma unroll
      for (int c = 0; c < 2; ++c)
        bfr[nt2][c] = *(const bf16x8*)(BB + row * 128 + (((c * 4 + g) ^ (row & 7)) << 4));
    }
    #pragma unroll
    for (int c = 0; c < 2; ++c)
      #pragma unroll
      for (int mt = 0; mt < 2; ++mt)
        #pragma unroll
        for (int nt2 = 0; nt2 < 4; ++nt2)
          acc[mt][nt2] = __builtin_amdgcn_mfma_f32_16x16x32_bf16(af[mt][c], bfr[nt2][c], acc[mt][nt2], 0, 0, 0);

    asm volatile("" ::: "memory");
    __builtin_amdgcn_s_barrier();
    bi ^= 1;
  }
#undef GSTAGE

  #pragma unroll
  for (int mt = 0; mt < 2; ++mt)
    #pragma unroll
    for (int r4 = 0; r4 < 4; ++r4) {
      const size_t row = (size_t)(m0 + wr + mt * 16 + 4 * g + r4);
      #pragma unroll
      for (int nt2 = 0; nt2 < 4; ++nt2)
        C[row * Nn + n0 + wc + nt2 * 16 + l15] = acc[mt][nt2][r4];
    }
}

// ---------------------------------------------------------------------------
// qkv GEMM v4 with fused RoPE + layout epilogue. Same BK=64 swizzled body.
// Grid (64, 12): regions 0..7=q (pre-scaled by 0.125*log2e), 8..9=k, 10..11=v.
// ---------------------------------------------------------------------------
__global__ __launch_bounds__(256) void gemm_qkv_rope_kernel(
    const bf16* __restrict__ A, const bf16* __restrict__ Bt,
    const float* __restrict__ fc, const float* __restrict__ fs,
    bf16* __restrict__ qb, bf16* __restrict__ kb, bf16* __restrict__ vt)
{
  __shared__ __align__(16) bf16 As[2][64 * 64];
  __shared__ __align__(16) bf16 Bs[2][128 * 64];
  const int tid = threadIdx.x;
  const int lane = tid & 63;
  const int l15 = lane & 15;
  const int g = lane >> 4;
  const int wid = tid >> 6;
  const int wr = (wid >> 1) * 32;
  const int wc = (wid & 1) * 64;
  const int m0 = blockIdx.x * 64;
  const int n0 = blockIdx.y * 128;
  const int Kk = CD;

  f32x4 acc[2][4];
  #pragma unroll
  for (int i = 0; i < 2; ++i)
    #pragma unroll
    for (int j = 0; j < 4; ++j)
      acc[i][j] = (f32x4){0.f, 0.f, 0.f, 0.f};

  const int slr = tid >> 3;
  const int scg = (tid & 7) ^ (slr & 7);
  const bf16* aStage = A + (size_t)(m0 + slr) * Kk + scg * 8;
  const bf16* bStage = Bt + (size_t)(n0 + slr) * Kk + scg * 8;
  char* aDst = (char*)As + wid * 1024;
  char* bDst = (char*)Bs + wid * 1024;

#define GSTAGE(bi, k0) do {                                                   \
    gload_lds16(aStage + (k0),                      aDst + (bi) * 8192);      \
    gload_lds16(aStage + 32 * (size_t)Kk + (k0),    aDst + (bi) * 8192 + 4096); \
    gload_lds16(bStage + (k0),                      bDst + (bi) * 16384);     \
    gload_lds16(bStage + 32 * (size_t)Kk + (k0),    bDst + (bi) * 16384 + 4096); \
    gload_lds16(bStage + 64 * (size_t)Kk + (k0),    bDst + (bi) * 16384 + 8192); \
    gload_lds16(bStage + 96 * (size_t)Kk + (k0),    bDst + (bi) * 16384 + 12288); \
  } while (0)

  const int nt = Kk >> 6;
  int bi = 0;
  GSTAGE(0, 0);
  for (int t = 0; t < nt; ++t) {
    if (t + 1 < nt) {
      GSTAGE(bi ^ 1, (t + 1) * 64);
      asm volatile("s_waitcnt vmcnt(6)" ::: "memory");
    } else {
      asm volatile("s_waitcnt vmcnt(0)" ::: "memory");
    }
    __builtin_amdgcn_s_barrier();
    asm volatile("" ::: "memory");

    const char* AB = (const char*)As + bi * 8192;
    const char* BB = (const char*)Bs + bi * 16384;
    bf16x8 af[2][2], bfr[4][2];
    #pragma unroll
    for (int mt = 0; mt < 2; ++mt) {
      int row = wr + mt * 16 + l15;
      #pragma unroll
      for (int c = 0; c < 2; ++c)
        af[mt][c] = *(const bf16x8*)(AB + row * 128 + (((c * 4 + g) ^ (row & 7)) << 4));
    }
    #pragma unroll
    for (int nt2 = 0; nt2 < 4; ++nt2) {
      int row = wc + nt2 * 16 + l15;
      #pragma unroll
      for (int c = 0; c < 2; ++c)
        bfr[nt2][c] = *(const bf16x8*)(BB + row * 128 + (((c * 4 + g) ^ (row & 7)) << 4));
    }
    #pragma unroll
    for (int c = 0; c < 2; ++c)
      #pragma unroll
      for (int mt = 0; mt < 2; ++mt)
        #pragma unroll
        for (int nt2 = 0; nt2 < 4; ++nt2)
          acc[mt][nt2] = __builtin_amdgcn_mfma_f32_16x16x32_bf16(af[mt][c], bfr[nt2][c], acc[mt][nt2], 0, 0, 0);

    asm volatile("" ::: "memory");
    __builtin_amdgcn_s_barrier();
    bi ^= 1;
  }
#undef GSTAGE

  if (blockIdx.y < 10) {
    const bool isq = (blockIdx.y < 8);
    const float qsc = isq ? 0.18033688f : 1.0f;   // 0.125*log2(e) folded into q
    #pragma unroll
    for (int mt = 0; mt < 2; ++mt)
      #pragma unroll
      for (int r4 = 0; r4 < 4; ++r4) {
        int m = m0 + wr + mt * 16 + 4 * g + r4;
        int s = m & (CS - 1), bb = m >> 11;
        #pragma unroll
        for (int nt2 = 0; nt2 < 4; ++nt2) {
          int n = n0 + wc + nt2 * 16 + l15;
          int d = n & 63;
          float val = acc[mt][nt2][r4];
          float par = __shfl_xor(val, 1, 64);
          float cv = fc[s * 32 + (d >> 1)];
          float sv = fs[s * 32 + (d >> 1)];
          float o = (d & 1) ? (par * sv + val * cv) : (val * cv - par * sv);
          o *= qsc;
          if (isq) {
            int h = n >> 6;
            ((unsigned short*)qb)[(((size_t)bb * CH + h) * CS + s) * CHD + d] = f2bf(o);
          } else {
            int kh = (n >> 6) - 16;
            ((unsigned short*)kb)[(((size_t)bb * CKH + kh) * CS + s) * CHD + d] = f2bf(o);
          }
        }
      }
  } else {
    #pragma unroll
    for (int mt = 0; mt < 2; ++mt) {
      int mb = m0 + wr + mt * 16 + 4 * g;
      int s0 = mb & (CS - 1), bb = mb >> 11;
      #pragma unroll
      for (int nt2 = 0; nt2 < 4; ++nt2) {
        int n = n0 + wc + nt2 * 16 + l15;
        int d = n & 63;
        int kh = (n >> 6) - 20;
        ushort4 pk = make_ushort4(f2bf(acc[mt][nt2][0]), f2bf(acc[mt][nt2][1]),
                                  f2bf(acc[mt][nt2][2]), f2bf(acc[mt][nt2][3]));
        *(ushort4*)&((unsigned short*)vt)[(((size_t)bb * CKH + kh) * CHD + d) * CS + s0] = pk;
      }
    }
  }
}

// ---------------------------------------------------------------------------
// Merged prep (R13-proven): conv_x (blocks 0..2047) + 4 weight transposes.
// ---------------------------------------------------------------------------
__global__ __launch_bounds__(256) void prep_kernel(
    const float* __restrict__ x, bf16* __restrict__ xb,
    const float* __restrict__ wq, const float* __restrict__ wk,
    const float* __restrict__ wv, const float* __restrict__ wo,
    bf16* __restrict__ wqkvt, bf16* __restrict__ wot)
{
  const int tid = threadIdx.x;
  int bid = blockIdx.x;
  if (bid < 2048) {
    int i = (bid * 256 + tid) * 8;
    float4 a = *(const float4*)&x[i];
    float4 b = *(const float4*)&x[i + 4];
    unsigned short* o = (unsigned short*)xb + i;
    *(ushort4*)o = make_ushort4(f2bf(a.x), f2bf(a.y), f2bf(a.z), f2bf(a.w));
    *(ushort4*)(o + 4) = make_ushort4(f2bf(b.x), f2bf(b.y), f2bf(b.z), f2bf(b.w));
    return;
  }
  bid -= 2048;
  const float* W; bf16* Wt; int Nn, bx, by;
  if (bid < 256)      { W = wq; Wt = wqkvt;                      Nn = 1024; bx = bid & 15;        by = bid >> 4; }
  else if (bid < 320) { W = wk; Wt = wqkvt + (size_t)1024 * CD;  Nn = 256;  bx = (bid-256) & 15;  by = (bid-256) >> 4; }
  else if (bid < 384) { W = wv; Wt = wqkvt + (size_t)1280 * CD;  Nn = 256;  bx = (bid-320) & 15;  by = (bid-320) >> 4; }
  else                { W = wo; Wt = wot;                        Nn = 1024; bx = (bid-384) & 15;  by = (bid-384) >> 4; }
  const int Kk = 1024;
  const int k0 = bx * 64;
  const int n0 = by * 64;

  __shared__ float T[64][65];
  const int lr = tid >> 4;
  const int lc = (tid & 15) * 4;
  #pragma unroll
  for (int i = 0; i < 4; ++i) {
    float4 v = *(const float4*)&W[(size_t)(k0 + lr + i * 16) * Nn + n0 + lc];
    T[lr + i * 16][lc + 0] = v.x;
    T[lr + i * 16][lc + 1] = v.y;
    T[lr + i * 16][lc + 2] = v.z;
    T[lr + i * 16][lc + 3] = v.w;
  }
  __syncthreads();
  const int rn = tid >> 3;
  const int ck = (tid & 7) * 8;
  #pragma unroll
  for (int i = 0; i < 2; ++i) {
    int nn = rn + i * 32;
    unsigned short u[8];
    #pragma unroll
    for (int e = 0; e < 8; ++e) u[e] = f2bf(T[ck + e][nn]);
    unsigned short* dst = (unsigned short*)Wt + (size_t)(n0 + nn) * Kk + k0 + ck;
    *(ushort4*)dst = make_ushort4(u[0], u[1], u[2], u[3]);
    *(ushort4*)(dst + 4) = make_ushort4(u[4], u[5], u[6], u[7]);
  }
}

// ---------------------------------------------------------------------------
// MFMA flash attention, cross-block split-KV x2 (R16-proven) + T5 setprio
// around MFMA clusters (independent blocks at different phases -> m191 regime).
// ---------------------------------------------------------------------------
__global__ __launch_bounds__(256, 2) void flash_split_kernel(
    const bf16* __restrict__ qb, const bf16* __restrict__ kb,
    const bf16* __restrict__ vt, bf16* __restrict__ oc0,
    bf16* __restrict__ ob, float2* __restrict__ ml)
{
  __shared__ __align__(16) char arena[51200];
  char* KL = arena;                       // [2][8192]: K tile 64x(64 bf16)
  char* VL = arena + 16384;               // [2][8192]: V^T tile 64x(64 bf16)
  const int tid = threadIdx.x;
  const int lane = tid & 63;
  const int wid = tid >> 6;
  unsigned short* PLW = (unsigned short*)(arena + 32768) + wid * 2304; // [32][72]
  const int l15 = lane & 15;
  const int g = lane >> 4;
  const int blk = blockIdx.x;
  const int chunk = blk & 1;
  const int grp = (blk >> 1) & 7;         // b*4+kh
  const int idx = blk >> 4;               // 0..63
  const int qt = 63 - idx;                // longest pairs first
  const int kh = grp & 3;
  const int b = grp >> 2;
  const int h = kh * CREP + wid;
  const int N64 = (qt >> 1) + 1;
  const int hc = N64 >> 1;
  const int tbeg = chunk ? hc : 0;
  const int tend = chunk ? N64 : hc;

  const bf16* qbase = qb + ((size_t)(b * CH + h) * CS + qt * 32) * CHD;
  const bf16* kbase = kb + (size_t)(b * CKH + kh) * CS * CHD;
  const bf16* vbase = vt + (size_t)(b * CKH + kh) * CHD * CS;  // [d][s]

  bf16x8 qf[2][2];
  #pragma unroll
  for (int qs = 0; qs < 2; ++qs)
    #pragma unroll
    for (int c = 0; c < 2; ++c)
      qf[qs][c] = *(const bf16x8*)(qbase + (qs * 16 + l15) * CHD + c * 32 + g * 8);

  bf16x8 ones;
  #pragma unroll
  for (int e = 0; e < 8; ++e) ones[e] = (short)0x3F80;  // bf16 1.0

  f32x4 oacc[2][4];
  f32x4 lacc[2];
  #pragma unroll
  for (int qs = 0; qs < 2; ++qs) {
    lacc[qs] = (f32x4){0.f, 0.f, 0.f, 0.f};
    #pragma unroll
    for (int dt = 0; dt < 4; ++dt)
      oacc[qs][dt] = (f32x4){0.f, 0.f, 0.f, 0.f};
  }
  float mrow[2] = {-1e30f, -1e30f};

  const int slr = tid >> 3;
  const int scg = (tid & 7) ^ (slr & 7);
  const bf16* kstage = kbase + (size_t)slr * CHD + scg * 8;
  const bf16* vstage = vbase + (size_t)slr * CS + scg * 8;
  char* kdst = KL + wid * 1024;
  char* vdst = VL + wid * 1024;

#define STAGE(bi, t64) do {                                        \
    const bf16* ks_ = kstage + (size_t)(t64) * 64 * CHD;           \
    const bf16* vs_ = vstage + (t64) * 64;                         \
    gload_lds16(ks_,            kdst + (bi) * 8192);               \
    gload_lds16(ks_ + 32 * CHD, kdst + (bi) * 8192 + 4096);        \
    gload_lds16(vs_,            vdst + (bi) * 8192);               \
    gload_lds16(vs_ + 32 * CS,  vdst + (bi) * 8192 + 4096);        \
  } while (0)

  if (tbeg < tend) {
    int bi = 0;
    STAGE(0, tbeg);
    for (int t = tbeg; t < tend; ++t) {
      if (t + 1 < tend) {
        STAGE(bi ^ 1, t + 1);
        asm volatile("s_waitcnt vmcnt(4)" ::: "memory");
      } else {
        asm volatile("s_waitcnt vmcnt(0)" ::: "memory");
      }
      __builtin_amdgcn_s_barrier();
      asm volatile("" ::: "memory");

      const char* KB = KL + bi * 8192;
      const char* VB = VL + bi * 8192;
      bf16x8 kfr[4][2], vfr[4][2];
      #pragma unroll
      for (int kt = 0; kt < 4; ++kt) {
        int row = kt * 16 + l15;
        #pragma unroll
        for (int c = 0; c < 2; ++c)
          kfr[kt][c] = *(const bf16x8*)(KB + row * 128 + (((c * 4 + g) ^ (row & 7)) << 4));
      }
      #pragma unroll
      for (int dt = 0; dt < 4; ++dt) {
        int row = dt * 16 + l15;
        #pragma unroll
        for (int st = 0; st < 2; ++st)
          vfr[dt][st] = *(const bf16x8*)(VB + row * 128 + (((st * 4 + g) ^ (row & 7)) << 4));
      }

      // QK^T (swapped): S^T[k][q] — exp2 domain (Q pre-scaled)
      f32x4 sacc[4][2];
      #pragma unroll
      for (int kt = 0; kt < 4; ++kt)
        #pragma unroll
        for (int qs = 0; qs < 2; ++qs)
          sacc[kt][qs] = (f32x4){0.f, 0.f, 0.f, 0.f};
      __builtin_amdgcn_s_setprio(1);
      #pragma unroll
      for (int c = 0; c < 2; ++c)
        #pragma unroll
        for (int kt = 0; kt < 4; ++kt)
          #pragma unroll
          for (int qs = 0; qs < 2; ++qs)
            sacc[kt][qs] = __builtin_amdgcn_mfma_f32_16x16x32_bf16(kfr[kt][c], qf[qs][c], sacc[kt][qs], 0, 0, 0);
      __builtin_amdgcn_s_setprio(0);

      const bool diag = (t == N64 - 1);   // only reachable in chunk1
      #pragma unroll
      for (int qs = 0; qs < 2; ++qs) {
        float pe[16];
        float pm = -1e30f;
        #pragma unroll
        for (int kt = 0; kt < 4; ++kt)
          #pragma unroll
          for (int r = 0; r < 4; ++r) {
            float v = sacc[kt][qs][r];
            if (diag) {
              int koff = t * 64 + kt * 16 + 4 * g + r;
              if (koff > qt * 32 + qs * 16 + l15) v = -1e30f;
            }
            pe[kt * 4 + r] = v;
            pm = fmaxf(pm, v);
          }
        if (__any(pm > mrow[qs] + 8.0f)) {       // slow path: exact rescale
          pm = fmaxf(pm, __shfl_xor(pm, 16, 64));
          pm = fmaxf(pm, __shfl_xor(pm, 32, 64));
          float nm = fmaxf(mrow[qs], pm);
          float corr = exp2f(mrow[qs] - nm);
          mrow[qs] = nm;
          lacc[qs] *= corr;
          #pragma unroll
          for (int dt = 0; dt < 4; ++dt) oacc[qs][dt] *= corr;
        }
        #pragma unroll
        for (int i = 0; i < 16; ++i)
          pe[i] = exp2f(pe[i] - mrow[qs]);       // p <= 2^8
        // truncation pair-pack (bias cancels: l uses same truncated values)
        #pragma unroll
        for (int kt = 0; kt < 4; ++kt) {
          unsigned int lo = (__float_as_uint(pe[kt * 4 + 1]) & 0xFFFF0000u) |
                            (__float_as_uint(pe[kt * 4 + 0]) >> 16);
          unsigned int hi = (__float_as_uint(pe[kt * 4 + 3]) & 0xFFFF0000u) |
                            (__float_as_uint(pe[kt * 4 + 2]) >> 16);
          *(uint2*)&PLW[(qs * 16 + l15) * 72 + kt * 16 + 4 * g] = make_uint2(lo, hi);
        }
      }

      // PV + psum (same-wave LDS RAW)
      __builtin_amdgcn_s_setprio(1);
      #pragma unroll
      for (int qs = 0; qs < 2; ++qs) {
        #pragma unroll
        for (int st = 0; st < 2; ++st) {
          bf16x8 pf = *(const bf16x8*)&PLW[(qs * 16 + l15) * 72 + st * 32 + g * 8];
          lacc[qs] = __builtin_amdgcn_mfma_f32_16x16x32_bf16(ones, pf, lacc[qs], 0, 0, 0);
          #pragma unroll
          for (int dt = 0; dt < 4; ++dt)
            oacc[qs][dt] = __builtin_amdgcn_mfma_f32_16x16x32_bf16(vfr[dt][st], pf, oacc[qs][dt], 0, 0, 0);
        }
      }
      __builtin_amdgcn_s_setprio(0);

      asm volatile("" ::: "memory");
      __builtin_amdgcn_s_barrier();
      bi ^= 1;
    }
  }
#undef STAGE

  // partial write: unnormalized O (bf16) + (m,l). Kernel boundary = sync.
  unsigned short* pdst = (unsigned short*)(chunk ? ob : oc0);
  #pragma unroll
  for (int qs = 0; qs < 2; ++qs) {
    int qg = qt * 32 + qs * 16 + l15;
    unsigned short* prow = pdst + (size_t)(b * CS + qg) * CNQ + h * CHD;
    #pragma unroll
    for (int dt = 0; dt < 4; ++dt)
      *(ushort4*)&prow[dt * 16 + 4 * g] =
          make_ushort4(f2bf(oacc[qs][dt][0]), f2bf(oacc[qs][dt][1]),
                       f2bf(oacc[qs][dt][2]), f2bf(oacc[qs][dt][3]));
    if (g == 0)
      ml[(((size_t)chunk * CB + b) * CH + h) * CS + qg] = make_float2(mrow[qs], lacc[qs][0]);
  }
}

// ---------------------------------------------------------------------------
// Merge: final_o = (c0*o0 + c1*o1) / (c0*l0 + c1*l1), in-place over ob.
// ---------------------------------------------------------------------------
__global__ __launch_bounds__(256) void merge_kernel(
    const bf16* __restrict__ oc0, bf16* __restrict__ ob,
    const float2* __restrict__ ml)
{
  const int e8 = blockIdx.x * 256 + threadIdx.x;     // 0 .. 524287
  const size_t off = (size_t)e8 * 8;
  const int row = (int)(off >> 10);                  // b*CS + s
  const int col = (int)(off & 1023);
  const int h = col >> 6;
  const int b = row >> 11;
  const int s = row & (CS - 1);
  float2 ml0 = ml[(((size_t)0 * CB + b) * CH + h) * CS + s];
  float2 ml1 = ml[(((size_t)1 * CB + b) * CH + h) * CS + s];
  float M = fmaxf(ml0.x, ml1.x);
  float c0 = exp2f(ml0.x - M), c1 = exp2f(ml1.x - M);
  float inv = 1.0f / (c0 * ml0.y + c1 * ml1.y);
  ushort4 a0 = *(const ushort4*)((const unsigned short*)oc0 + off);
  ushort4 a1 = *(const ushort4*)((const unsigned short*)oc0 + off + 4);
  ushort4 b0 = *(const ushort4*)((const unsigned short*)ob + off);
  ushort4 b1 = *(const ushort4*)((const unsigned short*)ob + off + 4);
  unsigned short r[8];
  const unsigned short* p0 = &a0.x;
  const unsigned short* p1 = &b0.x;
  #pragma unroll
  for (int i = 0; i < 4; ++i)
    r[i] = f2bf((c0 * bf2f(p0[i]) + c1 * bf2f(p1[i])) * inv);
  p0 = &a1.x; p1 = &b1.x;
  #pragma unroll
  for (int i = 0; i < 4; ++i)
    r[4 + i] = f2bf((c0 * bf2f(p0[i]) + c1 * bf2f(p1[i])) * inv);
  *(ushort4*)((unsigned short*)ob + off) = make_ushort4(r[0], r[1], r[2], r[3]);
  *(ushort4*)((unsigned short*)ob + off + 4) = make_ushort4(r[4], r[5], r[6], r[7]);
}

// ---------------------------------------------------------------------------
extern "C" void kernel_launch(void* const* d_in, const int* in_sizes, int n_in,
                              void* d_out, int out_size, void* d_ws, size_t ws_size,
                              hipStream_t stream)
{
  const float* x  = (const float*)d_in[0];
  const float* wq = (const float*)d_in[1];
  const float* wk = (const float*)d_in[2];
  const float* wv = (const float*)d_in[3];
  const float* wo = (const float*)d_in[4];
  const float* fc = (const float*)d_in[5];
  const float* fs = (const float*)d_in[6];
  float* out = (float*)d_out;

  char* ws = (char*)d_ws;
  // workspace (peak ~34.6MB):
  bf16*   x_b   = (bf16*)(ws);
  bf16*   wqkvt = (bf16*)(ws + 8388608);
  bf16*   wot   = (bf16*)(ws + 11534336);
  bf16*   q_b   = (bf16*)(ws + 13631488);
  bf16*   k_b   = (bf16*)(ws + 22020096);
  bf16*   v_t   = (bf16*)(ws + 24117248);
  bf16*   o_b   = (bf16*)(ws);               // over x_b
  bf16*   oc0   = (bf16*)(ws + 26214400);
  float2* mlb   = (float2*)(ws + 34603008);

  prep_kernel<<<2688, 256, 0, stream>>>(x, x_b, wq, wk, wv, wo, wqkvt, wot);
  gemm_qkv_rope_kernel<<<dim3(64, 12), 256, 0, stream>>>(x_b, wqkvt, fc, fs, q_b, k_b, v_t);
  flash_split_kernel<<<1024, 256, 0, stream>>>(q_b, k_b, v_t, oc0, o_b, mlb);
  merge_kernel<<<2048, 256, 0, stream>>>(oc0, o_b, mlb);
  gemm_mfma_kernel<<<dim3(64, 8), 256, 0, stream>>>(o_b, wot, out, CM, CD, CNQ, CNQ);
}

// Round 19
// 98.905 us; speedup vs baseline: 3.6861x; 1.0721x over previous
//
#include <hip/hip_runtime.h>
#include <hip/hip_bf16.h>

using bf16 = __hip_bfloat16;
typedef short bf16x8 __attribute__((ext_vector_type(8)));
typedef short bf16x4 __attribute__((ext_vector_type(4)));
typedef float f32x4 __attribute__((ext_vector_type(4)));

#define CB 2
#define CS 2048
#define CD 1024
#define CH 16
#define CKH 4
#define CHD 64
#define CREP 4
#define CNQ (CH*CHD)    // 1024
#define CNKV (CKH*CHD)  // 256
#define CM (CB*CS)      // 4096

__device__ __forceinline__ unsigned short f2bf(float f) {
  union { float f; unsigned int i; } c; c.f = f;
  unsigned int r = c.i + 0x7FFFu + ((c.i >> 16) & 1u);  // RNE
  return (unsigned short)(r >> 16);
}
__device__ __forceinline__ float bf2f(unsigned short u) {
  union { unsigned int i; float f; } c;
  c.i = ((unsigned int)u) << 16;
  return c.f;
}
__device__ __forceinline__ void gload_lds16(const void* g, void* l) {
  __builtin_amdgcn_global_load_lds(
      (const __attribute__((address_space(1))) void*)g,
      (__attribute__((address_space(3))) void*)l, 16, 0, 0);
}
// K=16 bf16 MFMA: 4 bf16/lane per operand (k = 4*(lane>>4) + elem canonical
// map; both operands below use the SAME map, so the HW k-mapping cancels).
__device__ __forceinline__ f32x4 mfma16bf16(bf16x4 a, bf16x4 b, f32x4 c) {
#if __has_builtin(__builtin_amdgcn_mfma_f32_16x16x16_bf16)
  return __builtin_amdgcn_mfma_f32_16x16x16_bf16(a, b, c, 0, 0, 0);
#elif __has_builtin(__builtin_amdgcn_mfma_f32_16x16x16bf16_1k)
  return __builtin_amdgcn_mfma_f32_16x16x16bf16_1k(a, b, c, 0, 0, 0);
#else
  asm("v_mfma_f32_16x16x16_bf16 %0, %1, %2, %0" : "+v"(c) : "v"(a), "v"(b));
  return c;
#endif
}

// ---------------------------------------------------------------------------
// bf16 MFMA GEMM v4 (R18-proven): 64x128 tile, BK=64, XOR-swizzled LDS.
// ---------------------------------------------------------------------------
__global__ __launch_bounds__(256) void gemm_mfma_kernel(
    const bf16* __restrict__ A, const bf16* __restrict__ Bt,
    float* __restrict__ C, int Mm, int Nn, int Kk, int lda)
{
  __shared__ __align__(16) bf16 As[2][64 * 64];
  __shared__ __align__(16) bf16 Bs[2][128 * 64];
  const int tid = threadIdx.x;
  const int lane = tid & 63;
  const int l15 = lane & 15;
  const int g = lane >> 4;
  const int wid = tid >> 6;
  const int wr = (wid >> 1) * 32;
  const int wc = (wid & 1) * 64;
  const int m0 = blockIdx.x * 64;
  const int n0 = blockIdx.y * 128;

  f32x4 acc[2][4];
  #pragma unroll
  for (int i = 0; i < 2; ++i)
    #pragma unroll
    for (int j = 0; j < 4; ++j)
      acc[i][j] = (f32x4){0.f, 0.f, 0.f, 0.f};

  const int slr = tid >> 3;
  const int scg = (tid & 7) ^ (slr & 7);
  const bf16* aStage = A + (size_t)(m0 + slr) * lda + scg * 8;
  const bf16* bStage = Bt + (size_t)(n0 + slr) * Kk + scg * 8;
  char* aDst = (char*)As + wid * 1024;
  char* bDst = (char*)Bs + wid * 1024;

#define GSTAGE(bi, k0) do {                                                   \
    gload_lds16(aStage + (k0),                      aDst + (bi) * 8192);      \
    gload_lds16(aStage + 32 * (size_t)lda + (k0),   aDst + (bi) * 8192 + 4096); \
    gload_lds16(bStage + (k0),                      bDst + (bi) * 16384);     \
    gload_lds16(bStage + 32 * (size_t)Kk + (k0),    bDst + (bi) * 16384 + 4096); \
    gload_lds16(bStage + 64 * (size_t)Kk + (k0),    bDst + (bi) * 16384 + 8192); \
    gload_lds16(bStage + 96 * (size_t)Kk + (k0),    bDst + (bi) * 16384 + 12288); \
  } while (0)

  const int nt = Kk >> 6;
  int bi = 0;
  GSTAGE(0, 0);
  for (int t = 0; t < nt; ++t) {
    if (t + 1 < nt) {
      GSTAGE(bi ^ 1, (t + 1) * 64);
      asm volatile("s_waitcnt vmcnt(6)" ::: "memory");
    } else {
      asm volatile("s_waitcnt vmcnt(0)" ::: "memory");
    }
    __builtin_amdgcn_s_barrier();
    asm volatile("" ::: "memory");

    const char* AB = (const char*)As + bi * 8192;
    const char* BB = (const char*)Bs + bi * 16384;
    bf16x8 af[2][2], bfr[4][2];
    #pragma unroll
    for (int mt = 0; mt < 2; ++mt) {
      int row = wr + mt * 16 + l15;
      #pragma unroll
      for (int c = 0; c < 2; ++c)
        af[mt][c] = *(const bf16x8*)(AB + row * 128 + (((c * 4 + g) ^ (row & 7)) << 4));
    }
    #pragma unroll
    for (int nt2 = 0; nt2 < 4; ++nt2) {
      int row = wc + nt2 * 16 + l15;
      #pragma unroll
      for (int c = 0; c < 2; ++c)
        bfr[nt2][c] = *(const bf16x8*)(BB + row * 128 + (((c * 4 + g) ^ (row & 7)) << 4));
    }
    #pragma unroll
    for (int c = 0; c < 2; ++c)
      #pragma unroll
      for (int mt = 0; mt < 2; ++mt)
        #pragma unroll
        for (int nt2 = 0; nt2 < 4; ++nt2)
          acc[mt][nt2] = __builtin_amdgcn_mfma_f32_16x16x32_bf16(af[mt][c], bfr[nt2][c], acc[mt][nt2], 0, 0, 0);

    asm volatile("" ::: "memory");
    __builtin_amdgcn_s_barrier();
    bi ^= 1;
  }
#undef GSTAGE

  #pragma unroll
  for (int mt = 0; mt < 2; ++mt)
    #pragma unroll
    for (int r4 = 0; r4 < 4; ++r4) {
      const size_t row = (size_t)(m0 + wr + mt * 16 + 4 * g + r4);
      #pragma unroll
      for (int nt2 = 0; nt2 < 4; ++nt2)
        C[row * Nn + n0 + wc + nt2 * 16 + l15] = acc[mt][nt2][r4];
    }
}

// ---------------------------------------------------------------------------
// qkv GEMM v4 with fused RoPE + layout epilogue (R18-proven).
// ---------------------------------------------------------------------------
__global__ __launch_bounds__(256) void gemm_qkv_rope_kernel(
    const bf16* __restrict__ A, const bf16* __restrict__ Bt,
    const float* __restrict__ fc, const float* __restrict__ fs,
    bf16* __restrict__ qb, bf16* __restrict__ kb, bf16* __restrict__ vt)
{
  __shared__ __align__(16) bf16 As[2][64 * 64];
  __shared__ __align__(16) bf16 Bs[2][128 * 64];
  const int tid = threadIdx.x;
  const int lane = tid & 63;
  const int l15 = lane & 15;
  const int g = lane >> 4;
  const int wid = tid >> 6;
  const int wr = (wid >> 1) * 32;
  const int wc = (wid & 1) * 64;
  const int m0 = blockIdx.x * 64;
  const int n0 = blockIdx.y * 128;
  const int Kk = CD;

  f32x4 acc[2][4];
  #pragma unroll
  for (int i = 0; i < 2; ++i)
    #pragma unroll
    for (int j = 0; j < 4; ++j)
      acc[i][j] = (f32x4){0.f, 0.f, 0.f, 0.f};

  const int slr = tid >> 3;
  const int scg = (tid & 7) ^ (slr & 7);
  const bf16* aStage = A + (size_t)(m0 + slr) * Kk + scg * 8;
  const bf16* bStage = Bt + (size_t)(n0 + slr) * Kk + scg * 8;
  char* aDst = (char*)As + wid * 1024;
  char* bDst = (char*)Bs + wid * 1024;

#define GSTAGE(bi, k0) do {                                                   \
    gload_lds16(aStage + (k0),                      aDst + (bi) * 8192);      \
    gload_lds16(aStage + 32 * (size_t)Kk + (k0),    aDst + (bi) * 8192 + 4096); \
    gload_lds16(bStage + (k0),                      bDst + (bi) * 16384);     \
    gload_lds16(bStage + 32 * (size_t)Kk + (k0),    bDst + (bi) * 16384 + 4096); \
    gload_lds16(bStage + 64 * (size_t)Kk + (k0),    bDst + (bi) * 16384 + 8192); \
    gload_lds16(bStage + 96 * (size_t)Kk + (k0),    bDst + (bi) * 16384 + 12288); \
  } while (0)

  const int nt = Kk >> 6;
  int bi = 0;
  GSTAGE(0, 0);
  for (int t = 0; t < nt; ++t) {
    if (t + 1 < nt) {
      GSTAGE(bi ^ 1, (t + 1) * 64);
      asm volatile("s_waitcnt vmcnt(6)" ::: "memory");
    } else {
      asm volatile("s_waitcnt vmcnt(0)" ::: "memory");
    }
    __builtin_amdgcn_s_barrier();
    asm volatile("" ::: "memory");

    const char* AB = (const char*)As + bi * 8192;
    const char* BB = (const char*)Bs + bi * 16384;
    bf16x8 af[2][2], bfr[4][2];
    #pragma unroll
    for (int mt = 0; mt < 2; ++mt) {
      int row = wr + mt * 16 + l15;
      #pragma unroll
      for (int c = 0; c < 2; ++c)
        af[mt][c] = *(const bf16x8*)(AB + row * 128 + (((c * 4 + g) ^ (row & 7)) << 4));
    }
    #pragma unroll
    for (int nt2 = 0; nt2 < 4; ++nt2) {
      int row = wc + nt2 * 16 + l15;
      #pragma unroll
      for (int c = 0; c < 2; ++c)
        bfr[nt2][c] = *(const bf16x8*)(BB + row * 128 + (((c * 4 + g) ^ (row & 7)) << 4));
    }
    #pragma unroll
    for (int c = 0; c < 2; ++c)
      #pragma unroll
      for (int mt = 0; mt < 2; ++mt)
        #pragma unroll
        for (int nt2 = 0; nt2 < 4; ++nt2)
          acc[mt][nt2] = __builtin_amdgcn_mfma_f32_16x16x32_bf16(af[mt][c], bfr[nt2][c], acc[mt][nt2], 0, 0, 0);

    asm volatile("" ::: "memory");
    __builtin_amdgcn_s_barrier();
    bi ^= 1;
  }
#undef GSTAGE

  if (blockIdx.y < 10) {
    const bool isq = (blockIdx.y < 8);
    const float qsc = isq ? 0.18033688f : 1.0f;   // 0.125*log2(e) folded into q
    #pragma unroll
    for (int mt = 0; mt < 2; ++mt)
      #pragma unroll
      for (int r4 = 0; r4 < 4; ++r4) {
        int m = m0 + wr + mt * 16 + 4 * g + r4;
        int s = m & (CS - 1), bb = m >> 11;
        #pragma unroll
        for (int nt2 = 0; nt2 < 4; ++nt2) {
          int n = n0 + wc + nt2 * 16 + l15;
          int d = n & 63;
          float val = acc[mt][nt2][r4];
          float par = __shfl_xor(val, 1, 64);
          float cv = fc[s * 32 + (d >> 1)];
          float sv = fs[s * 32 + (d >> 1)];
          float o = (d & 1) ? (par * sv + val * cv) : (val * cv - par * sv);
          o *= qsc;
          if (isq) {
            int h = n >> 6;
            ((unsigned short*)qb)[(((size_t)bb * CH + h) * CS + s) * CHD + d] = f2bf(o);
          } else {
            int kh = (n >> 6) - 16;
            ((unsigned short*)kb)[(((size_t)bb * CKH + kh) * CS + s) * CHD + d] = f2bf(o);
          }
        }
      }
  } else {
    #pragma unroll
    for (int mt = 0; mt < 2; ++mt) {
      int mb = m0 + wr + mt * 16 + 4 * g;
      int s0 = mb & (CS - 1), bb = mb >> 11;
      #pragma unroll
      for (int nt2 = 0; nt2 < 4; ++nt2) {
        int n = n0 + wc + nt2 * 16 + l15;
        int d = n & 63;
        int kh = (n >> 6) - 20;
        ushort4 pk = make_ushort4(f2bf(acc[mt][nt2][0]), f2bf(acc[mt][nt2][1]),
                                  f2bf(acc[mt][nt2][2]), f2bf(acc[mt][nt2][3]));
        *(ushort4*)&((unsigned short*)vt)[(((size_t)bb * CKH + kh) * CHD + d) * CS + s0] = pk;
      }
    }
  }
}

// ---------------------------------------------------------------------------
// Merged prep (R13-proven): conv_x (blocks 0..2047) + 4 weight transposes.
// ---------------------------------------------------------------------------
__global__ __launch_bounds__(256) void prep_kernel(
    const float* __restrict__ x, bf16* __restrict__ xb,
    const float* __restrict__ wq, const float* __restrict__ wk,
    const float* __restrict__ wv, const float* __restrict__ wo,
    bf16* __restrict__ wqkvt, bf16* __restrict__ wot)
{
  const int tid = threadIdx.x;
  int bid = blockIdx.x;
  if (bid < 2048) {
    int i = (bid * 256 + tid) * 8;
    float4 a = *(const float4*)&x[i];
    float4 b = *(const float4*)&x[i + 4];
    unsigned short* o = (unsigned short*)xb + i;
    *(ushort4*)o = make_ushort4(f2bf(a.x), f2bf(a.y), f2bf(a.z), f2bf(a.w));
    *(ushort4*)(o + 4) = make_ushort4(f2bf(b.x), f2bf(b.y), f2bf(b.z), f2bf(b.w));
    return;
  }
  bid -= 2048;
  const float* W; bf16* Wt; int Nn, bx, by;
  if (bid < 256)      { W = wq; Wt = wqkvt;                      Nn = 1024; bx = bid & 15;        by = bid >> 4; }
  else if (bid < 320) { W = wk; Wt = wqkvt + (size_t)1024 * CD;  Nn = 256;  bx = (bid-256) & 15;  by = (bid-256) >> 4; }
  else if (bid < 384) { W = wv; Wt = wqkvt + (size_t)1280 * CD;  Nn = 256;  bx = (bid-320) & 15;  by = (bid-320) >> 4; }
  else                { W = wo; Wt = wot;                        Nn = 1024; bx = (bid-384) & 15;  by = (bid-384) >> 4; }
  const int Kk = 1024;
  const int k0 = bx * 64;
  const int n0 = by * 64;

  __shared__ float T[64][65];
  const int lr = tid >> 4;
  const int lc = (tid & 15) * 4;
  #pragma unroll
  for (int i = 0; i < 4; ++i) {
    float4 v = *(const float4*)&W[(size_t)(k0 + lr + i * 16) * Nn + n0 + lc];
    T[lr + i * 16][lc + 0] = v.x;
    T[lr + i * 16][lc + 1] = v.y;
    T[lr + i * 16][lc + 2] = v.z;
    T[lr + i * 16][lc + 3] = v.w;
  }
  __syncthreads();
  const int rn = tid >> 3;
  const int ck = (tid & 7) * 8;
  #pragma unroll
  for (int i = 0; i < 2; ++i) {
    int nn = rn + i * 32;
    unsigned short u[8];
    #pragma unroll
    for (int e = 0; e < 8; ++e) u[e] = f2bf(T[ck + e][nn]);
    unsigned short* dst = (unsigned short*)Wt + (size_t)(n0 + nn) * Kk + k0 + ck;
    *(ushort4*)dst = make_ushort4(u[0], u[1], u[2], u[3]);
    *(ushort4*)(dst + 4) = make_ushort4(u[4], u[5], u[6], u[7]);
  }
}

// ---------------------------------------------------------------------------
// MFMA flash attention, split-KV x2 (R16 structure), PV via K=16 MFMA:
// P stays in registers (C-layout rows k=kt*16+4g+r == K16-fragment shape),
// no P LDS round-trip; V read as swizzled ds_read_b64 with the SAME
// (lane,elem)->k map (HW k-mapping cancels). LDS 32KB -> 4 blocks/CU.
// No setprio (R18 A/B: regression).
// ---------------------------------------------------------------------------
__global__ __launch_bounds__(256, 2) void flash_split_kernel(
    const bf16* __restrict__ qb, const bf16* __restrict__ kb,
    const bf16* __restrict__ vt, bf16* __restrict__ oc0,
    bf16* __restrict__ ob, float2* __restrict__ ml)
{
  __shared__ __align__(16) char arena[32768];
  char* KL = arena;                       // [2][8192]: K tile 64x(64 bf16)
  char* VL = arena + 16384;               // [2][8192]: V^T tile 64x(64 bf16)
  const int tid = threadIdx.x;
  const int lane = tid & 63;
  const int wid = tid >> 6;
  const int l15 = lane & 15;
  const int g = lane >> 4;
  const int blk = blockIdx.x;
  const int chunk = blk & 1;
  const int grp = (blk >> 1) & 7;         // b*4+kh
  const int idx = blk >> 4;               // 0..63
  const int qt = 63 - idx;                // longest pairs first
  const int kh = grp & 3;
  const int b = grp >> 2;
  const int h = kh * CREP + wid;
  const int N64 = (qt >> 1) + 1;
  const int hc = N64 >> 1;
  const int tbeg = chunk ? hc : 0;
  const int tend = chunk ? N64 : hc;

  const bf16* qbase = qb + ((size_t)(b * CH + h) * CS + qt * 32) * CHD;
  const bf16* kbase = kb + (size_t)(b * CKH + kh) * CS * CHD;
  const bf16* vbase = vt + (size_t)(b * CKH + kh) * CHD * CS;  // [d][s]

  bf16x8 qf[2][2];
  #pragma unroll
  for (int qs = 0; qs < 2; ++qs)
    #pragma unroll
    for (int c = 0; c < 2; ++c)
      qf[qs][c] = *(const bf16x8*)(qbase + (qs * 16 + l15) * CHD + c * 32 + g * 8);

  bf16x4 ones4;
  #pragma unroll
  for (int e = 0; e < 4; ++e) ones4[e] = (short)0x3F80;  // bf16 1.0

  f32x4 oacc[2][4];
  f32x4 lacc[2];
  #pragma unroll
  for (int qs = 0; qs < 2; ++qs) {
    lacc[qs] = (f32x4){0.f, 0.f, 0.f, 0.f};
    #pragma unroll
    for (int dt = 0; dt < 4; ++dt)
      oacc[qs][dt] = (f32x4){0.f, 0.f, 0.f, 0.f};
  }
  float mrow[2] = {-1e30f, -1e30f};

  const int slr = tid >> 3;
  const int scg = (tid & 7) ^ (slr & 7);
  const bf16* kstage = kbase + (size_t)slr * CHD + scg * 8;
  const bf16* vstage = vbase + (size_t)slr * CS + scg * 8;
  char* kdst = KL + wid * 1024;
  char* vdst = VL + wid * 1024;

#define STAGE(bi, t64) do {                                        \
    const bf16* ks_ = kstage + (size_t)(t64) * 64 * CHD;           \
    const bf16* vs_ = vstage + (t64) * 64;                         \
    gload_lds16(ks_,            kdst + (bi) * 8192);               \
    gload_lds16(ks_ + 32 * CHD, kdst + (bi) * 8192 + 4096);        \
    gload_lds16(vs_,            vdst + (bi) * 8192);               \
    gload_lds16(vs_ + 32 * CS,  vdst + (bi) * 8192 + 4096);        \
  } while (0)

  if (tbeg < tend) {
    int bi = 0;
    STAGE(0, tbeg);
    for (int t = tbeg; t < tend; ++t) {
      if (t + 1 < tend) {
        STAGE(bi ^ 1, t + 1);
        asm volatile("s_waitcnt vmcnt(4)" ::: "memory");
      } else {
        asm volatile("s_waitcnt vmcnt(0)" ::: "memory");
      }
      __builtin_amdgcn_s_barrier();
      asm volatile("" ::: "memory");

      const char* KB = KL + bi * 8192;
      const char* VB = VL + bi * 8192;
      bf16x8 kfr[4][2];
      #pragma unroll
      for (int kt = 0; kt < 4; ++kt) {
        int row = kt * 16 + l15;
        #pragma unroll
        for (int c = 0; c < 2; ++c)
          kfr[kt][c] = *(const bf16x8*)(KB + row * 128 + (((c * 4 + g) ^ (row & 7)) << 4));
      }
      // V fragments for K16 PV: elem j of (lane) = V^T[d][kt*16 + 4g + j]
      // byte range [kt*32+8g, +8) -> 16B chunk 2kt+(g>>1), half g&1 (swizzled)
      bf16x4 vfr16[4][4];
      #pragma unroll
      for (int dt = 0; dt < 4; ++dt) {
        int row = dt * 16 + l15;
        #pragma unroll
        for (int kt = 0; kt < 4; ++kt)
          vfr16[dt][kt] = *(const bf16x4*)(VB + row * 128 +
              (((2 * kt + (g >> 1)) ^ (row & 7)) << 4) + (g & 1) * 8);
      }

      // QK^T (swapped): S^T[k][q] — exp2 domain (Q pre-scaled)
      f32x4 sacc[4][2];
      #pragma unroll
      for (int kt = 0; kt < 4; ++kt)
        #pragma unroll
        for (int qs = 0; qs < 2; ++qs)
          sacc[kt][qs] = (f32x4){0.f, 0.f, 0.f, 0.f};
      #pragma unroll
      for (int c = 0; c < 2; ++c)
        #pragma unroll
        for (int kt = 0; kt < 4; ++kt)
          #pragma unroll
          for (int qs = 0; qs < 2; ++qs)
            sacc[kt][qs] = __builtin_amdgcn_mfma_f32_16x16x32_bf16(kfr[kt][c], qf[qs][c], sacc[kt][qs], 0, 0, 0);

      const bool diag = (t == N64 - 1);   // only reachable in chunk1
      #pragma unroll
      for (int qs = 0; qs < 2; ++qs) {
        float pe[16];
        float pm = -1e30f;
        #pragma unroll
        for (int kt = 0; kt < 4; ++kt)
          #pragma unroll
          for (int r = 0; r < 4; ++r) {
            float v = sacc[kt][qs][r];
            if (diag) {
              int koff = t * 64 + kt * 16 + 4 * g + r;
              if (koff > qt * 32 + qs * 16 + l15) v = -1e30f;
            }
            pe[kt * 4 + r] = v;
            pm = fmaxf(pm, v);
          }
        if (__any(pm > mrow[qs] + 8.0f)) {       // slow path: exact rescale
          pm = fmaxf(pm, __shfl_xor(pm, 16, 64));
          pm = fmaxf(pm, __shfl_xor(pm, 32, 64));
          float nm = fmaxf(mrow[qs], pm);
          float corr = exp2f(mrow[qs] - nm);
          mrow[qs] = nm;
          lacc[qs] *= corr;
          #pragma unroll
          for (int dt = 0; dt < 4; ++dt) oacc[qs][dt] *= corr;
        }
        #pragma unroll
        for (int i = 0; i < 16; ++i)
          pe[i] = exp2f(pe[i] - mrow[qs]);       // p <= 2^8
        // truncation pair-pack into K16 P fragments (k = kt*16 + 4g + r)
        #pragma unroll
        for (int kt = 0; kt < 4; ++kt) {
          union { uint2 u; bf16x4 v; } cv;
          cv.u.x = (__float_as_uint(pe[kt * 4 + 1]) & 0xFFFF0000u) |
                   (__float_as_uint(pe[kt * 4 + 0]) >> 16);
          cv.u.y = (__float_as_uint(pe[kt * 4 + 3]) & 0xFFFF0000u) |
                   (__float_as_uint(pe[kt * 4 + 2]) >> 16);
          // PV + psum for this kt, straight from registers
          lacc[qs] = mfma16bf16(ones4, cv.v, lacc[qs]);
          #pragma unroll
          for (int dt = 0; dt < 4; ++dt)
            oacc[qs][dt] = mfma16bf16(vfr16[dt][kt], cv.v, oacc[qs][dt]);
        }
      }

      asm volatile("" ::: "memory");
      __builtin_amdgcn_s_barrier();
      bi ^= 1;
    }
  }
#undef STAGE

  // partial write: unnormalized O (bf16) + (m,l). Kernel boundary = sync.
  unsigned short* pdst = (unsigned short*)(chunk ? ob : oc0);
  #pragma unroll
  for (int qs = 0; qs < 2; ++qs) {
    int qg = qt * 32 + qs * 16 + l15;
    unsigned short* prow = pdst + (size_t)(b * CS + qg) * CNQ + h * CHD;
    #pragma unroll
    for (int dt = 0; dt < 4; ++dt)
      *(ushort4*)&prow[dt * 16 + 4 * g] =
          make_ushort4(f2bf(oacc[qs][dt][0]), f2bf(oacc[qs][dt][1]),
                       f2bf(oacc[qs][dt][2]), f2bf(oacc[qs][dt][3]));
    if (g == 0)
      ml[(((size_t)chunk * CB + b) * CH + h) * CS + qg] = make_float2(mrow[qs], lacc[qs][0]);
  }
}

// ---------------------------------------------------------------------------
// Merge: final_o = (c0*o0 + c1*o1) / (c0*l0 + c1*l1), in-place over ob.
// ---------------------------------------------------------------------------
__global__ __launch_bounds__(256) void merge_kernel(
    const bf16* __restrict__ oc0, bf16* __restrict__ ob,
    const float2* __restrict__ ml)
{
  const int e8 = blockIdx.x * 256 + threadIdx.x;     // 0 .. 524287
  const size_t off = (size_t)e8 * 8;
  const int row = (int)(off >> 10);                  // b*CS + s
  const int col = (int)(off & 1023);
  const int h = col >> 6;
  const int b = row >> 11;
  const int s = row & (CS - 1);
  float2 ml0 = ml[(((size_t)0 * CB + b) * CH + h) * CS + s];
  float2 ml1 = ml[(((size_t)1 * CB + b) * CH + h) * CS + s];
  float M = fmaxf(ml0.x, ml1.x);
  float c0 = exp2f(ml0.x - M), c1 = exp2f(ml1.x - M);
  float inv = 1.0f / (c0 * ml0.y + c1 * ml1.y);
  ushort4 a0 = *(const ushort4*)((const unsigned short*)oc0 + off);
  ushort4 a1 = *(const ushort4*)((const unsigned short*)oc0 + off + 4);
  ushort4 b0 = *(const ushort4*)((const unsigned short*)ob + off);
  ushort4 b1 = *(const ushort4*)((const unsigned short*)ob + off + 4);
  unsigned short r[8];
  const unsigned short* p0 = &a0.x;
  const unsigned short* p1 = &b0.x;
  #pragma unroll
  for (int i = 0; i < 4; ++i)
    r[i] = f2bf((c0 * bf2f(p0[i]) + c1 * bf2f(p1[i])) * inv);
  p0 = &a1.x; p1 = &b1.x;
  #pragma unroll
  for (int i = 0; i < 4; ++i)
    r[4 + i] = f2bf((c0 * bf2f(p0[i]) + c1 * bf2f(p1[i])) * inv);
  *(ushort4*)((unsigned short*)ob + off) = make_ushort4(r[0], r[1], r[2], r[3]);
  *(ushort4*)((unsigned short*)ob + off + 4) = make_ushort4(r[4], r[5], r[6], r[7]);
}

// ---------------------------------------------------------------------------
extern "C" void kernel_launch(void* const* d_in, const int* in_sizes, int n_in,
                              void* d_out, int out_size, void* d_ws, size_t ws_size,
                              hipStream_t stream)
{
  const float* x  = (const float*)d_in[0];
  const float* wq = (const float*)d_in[1];
  const float* wk = (const float*)d_in[2];
  const float* wv = (const float*)d_in[3];
  const float* wo = (const float*)d_in[4];
  const float* fc = (const float*)d_in[5];
  const float* fs = (const float*)d_in[6];
  float* out = (float*)d_out;

  char* ws = (char*)d_ws;
  // workspace (peak ~34.6MB):
  bf16*   x_b   = (bf16*)(ws);
  bf16*   wqkvt = (bf16*)(ws + 8388608);
  bf16*   wot   = (bf16*)(ws + 11534336);
  bf16*   q_b   = (bf16*)(ws + 13631488);
  bf16*   k_b   = (bf16*)(ws + 22020096);
  bf16*   v_t   = (bf16*)(ws + 24117248);
  bf16*   o_b   = (bf16*)(ws);               // over x_b
  bf16*   oc0   = (bf16*)(ws + 26214400);
  float2* mlb   = (float2*)(ws + 34603008);

  prep_kernel<<<2688, 256, 0, stream>>>(x, x_b, wq, wk, wv, wo, wqkvt, wot);
  gemm_qkv_rope_kernel<<<dim3(64, 12), 256, 0, stream>>>(x_b, wqkvt, fc, fs, q_b, k_b, v_t);
  flash_split_kernel<<<1024, 256, 0, stream>>>(q_b, k_b, v_t, oc0, o_b, mlb);
  merge_kernel<<<2048, 256, 0, stream>>>(oc0, o_b, mlb);
  gemm_mfma_kernel<<<dim3(64, 8), 256, 0, stream>>>(o_b, wot, out, CM, CD, CNQ, CNQ);
}

// Round 20
// 98.088 us; speedup vs baseline: 3.7168x; 1.0083x over previous
//
#include <hip/hip_runtime.h>
#include <hip/hip_bf16.h>

using bf16 = __hip_bfloat16;
typedef short bf16x8 __attribute__((ext_vector_type(8)));
typedef short bf16x4 __attribute__((ext_vector_type(4)));
typedef float f32x4 __attribute__((ext_vector_type(4)));

#define CB 2
#define CS 2048
#define CD 1024
#define CH 16
#define CKH 4
#define CHD 64
#define CREP 4
#define CNQ (CH*CHD)    // 1024
#define CNKV (CKH*CHD)  // 256
#define CM (CB*CS)      // 4096

__device__ __forceinline__ unsigned short f2bf(float f) {
  union { float f; unsigned int i; } c; c.f = f;
  unsigned int r = c.i + 0x7FFFu + ((c.i >> 16) & 1u);  // RNE
  return (unsigned short)(r >> 16);
}
__device__ __forceinline__ float bf2f(unsigned short u) {
  union { unsigned int i; float f; } c;
  c.i = ((unsigned int)u) << 16;
  return c.f;
}
__device__ __forceinline__ void gload_lds16(const void* g, void* l) {
  __builtin_amdgcn_global_load_lds(
      (const __attribute__((address_space(1))) void*)g,
      (__attribute__((address_space(3))) void*)l, 16, 0, 0);
}
// K=16 bf16 MFMA (R19-proven): 4 bf16/lane per operand; both operands use
// the same (lane,elem)->k map, so the HW k-mapping cancels.
__device__ __forceinline__ f32x4 mfma16bf16(bf16x4 a, bf16x4 b, f32x4 c) {
#if __has_builtin(__builtin_amdgcn_mfma_f32_16x16x16_bf16)
  return __builtin_amdgcn_mfma_f32_16x16x16_bf16(a, b, c, 0, 0, 0);
#elif __has_builtin(__builtin_amdgcn_mfma_f32_16x16x16bf16_1k)
  return __builtin_amdgcn_mfma_f32_16x16x16bf16_1k(a, b, c, 0, 0, 0);
#else
  asm("v_mfma_f32_16x16x16_bf16 %0, %1, %2, %0" : "+v"(c) : "v"(a), "v"(b));
  return c;
#endif
}

// ---------------------------------------------------------------------------
// bf16 MFMA GEMM v4 (R18-proven): 64x128 tile, BK=64, XOR-swizzled LDS.
// ---------------------------------------------------------------------------
__global__ __launch_bounds__(256) void gemm_mfma_kernel(
    const bf16* __restrict__ A, const bf16* __restrict__ Bt,
    float* __restrict__ C, int Mm, int Nn, int Kk, int lda)
{
  __shared__ __align__(16) bf16 As[2][64 * 64];
  __shared__ __align__(16) bf16 Bs[2][128 * 64];
  const int tid = threadIdx.x;
  const int lane = tid & 63;
  const int l15 = lane & 15;
  const int g = lane >> 4;
  const int wid = tid >> 6;
  const int wr = (wid >> 1) * 32;
  const int wc = (wid & 1) * 64;
  const int m0 = blockIdx.x * 64;
  const int n0 = blockIdx.y * 128;

  f32x4 acc[2][4];
  #pragma unroll
  for (int i = 0; i < 2; ++i)
    #pragma unroll
    for (int j = 0; j < 4; ++j)
      acc[i][j] = (f32x4){0.f, 0.f, 0.f, 0.f};

  const int slr = tid >> 3;
  const int scg = (tid & 7) ^ (slr & 7);
  const bf16* aStage = A + (size_t)(m0 + slr) * lda + scg * 8;
  const bf16* bStage = Bt + (size_t)(n0 + slr) * Kk + scg * 8;
  char* aDst = (char*)As + wid * 1024;
  char* bDst = (char*)Bs + wid * 1024;

#define GSTAGE(bi, k0) do {                                                   \
    gload_lds16(aStage + (k0),                      aDst + (bi) * 8192);      \
    gload_lds16(aStage + 32 * (size_t)lda + (k0),   aDst + (bi) * 8192 + 4096); \
    gload_lds16(bStage + (k0),                      bDst + (bi) * 16384);     \
    gload_lds16(bStage + 32 * (size_t)Kk + (k0),    bDst + (bi) * 16384 + 4096); \
    gload_lds16(bStage + 64 * (size_t)Kk + (k0),    bDst + (bi) * 16384 + 8192); \
    gload_lds16(bStage + 96 * (size_t)Kk + (k0),    bDst + (bi) * 16384 + 12288); \
  } while (0)

  const int nt = Kk >> 6;
  int bi = 0;
  GSTAGE(0, 0);
  for (int t = 0; t < nt; ++t) {
    if (t + 1 < nt) {
      GSTAGE(bi ^ 1, (t + 1) * 64);
      asm volatile("s_waitcnt vmcnt(6)" ::: "memory");
    } else {
      asm volatile("s_waitcnt vmcnt(0)" ::: "memory");
    }
    __builtin_amdgcn_s_barrier();
    asm volatile("" ::: "memory");

    const char* AB = (const char*)As + bi * 8192;
    const char* BB = (const char*)Bs + bi * 16384;
    bf16x8 af[2][2], bfr[4][2];
    #pragma unroll
    for (int mt = 0; mt < 2; ++mt) {
      int row = wr + mt * 16 + l15;
      #pragma unroll
      for (int c = 0; c < 2; ++c)
        af[mt][c] = *(const bf16x8*)(AB + row * 128 + (((c * 4 + g) ^ (row & 7)) << 4));
    }
    #pragma unroll
    for (int nt2 = 0; nt2 < 4; ++nt2) {
      int row = wc + nt2 * 16 + l15;
      #pragma unroll
      for (int c = 0; c < 2; ++c)
        bfr[nt2][c] = *(const bf16x8*)(BB + row * 128 + (((c * 4 + g) ^ (row & 7)) << 4));
    }
    #pragma unroll
    for (int c = 0; c < 2; ++c)
      #pragma unroll
      for (int mt = 0; mt < 2; ++mt)
        #pragma unroll
        for (int nt2 = 0; nt2 < 4; ++nt2)
          acc[mt][nt2] = __builtin_amdgcn_mfma_f32_16x16x32_bf16(af[mt][c], bfr[nt2][c], acc[mt][nt2], 0, 0, 0);

    asm volatile("" ::: "memory");
    __builtin_amdgcn_s_barrier();
    bi ^= 1;
  }
#undef GSTAGE

  #pragma unroll
  for (int mt = 0; mt < 2; ++mt)
    #pragma unroll
    for (int r4 = 0; r4 < 4; ++r4) {
      const size_t row = (size_t)(m0 + wr + mt * 16 + 4 * g + r4);
      #pragma unroll
      for (int nt2 = 0; nt2 < 4; ++nt2)
        C[row * Nn + n0 + wc + nt2 * 16 + l15] = acc[mt][nt2][r4];
    }
}

// ---------------------------------------------------------------------------
// qkv GEMM v4 with fused RoPE + layout epilogue (R18-proven).
// ---------------------------------------------------------------------------
__global__ __launch_bounds__(256) void gemm_qkv_rope_kernel(
    const bf16* __restrict__ A, const bf16* __restrict__ Bt,
    const float* __restrict__ fc, const float* __restrict__ fs,
    bf16* __restrict__ qb, bf16* __restrict__ kb, bf16* __restrict__ vt)
{
  __shared__ __align__(16) bf16 As[2][64 * 64];
  __shared__ __align__(16) bf16 Bs[2][128 * 64];
  const int tid = threadIdx.x;
  const int lane = tid & 63;
  const int l15 = lane & 15;
  const int g = lane >> 4;
  const int wid = tid >> 6;
  const int wr = (wid >> 1) * 32;
  const int wc = (wid & 1) * 64;
  const int m0 = blockIdx.x * 64;
  const int n0 = blockIdx.y * 128;
  const int Kk = CD;

  f32x4 acc[2][4];
  #pragma unroll
  for (int i = 0; i < 2; ++i)
    #pragma unroll
    for (int j = 0; j < 4; ++j)
      acc[i][j] = (f32x4){0.f, 0.f, 0.f, 0.f};

  const int slr = tid >> 3;
  const int scg = (tid & 7) ^ (slr & 7);
  const bf16* aStage = A + (size_t)(m0 + slr) * Kk + scg * 8;
  const bf16* bStage = Bt + (size_t)(n0 + slr) * Kk + scg * 8;
  char* aDst = (char*)As + wid * 1024;
  char* bDst = (char*)Bs + wid * 1024;

#define GSTAGE(bi, k0) do {                                                   \
    gload_lds16(aStage + (k0),                      aDst + (bi) * 8192);      \
    gload_lds16(aStage + 32 * (size_t)Kk + (k0),    aDst + (bi) * 8192 + 4096); \
    gload_lds16(bStage + (k0),                      bDst + (bi) * 16384);     \
    gload_lds16(bStage + 32 * (size_t)Kk + (k0),    bDst + (bi) * 16384 + 4096); \
    gload_lds16(bStage + 64 * (size_t)Kk + (k0),    bDst + (bi) * 16384 + 8192); \
    gload_lds16(bStage + 96 * (size_t)Kk + (k0),    bDst + (bi) * 16384 + 12288); \
  } while (0)

  const int nt = Kk >> 6;
  int bi = 0;
  GSTAGE(0, 0);
  for (int t = 0; t < nt; ++t) {
    if (t + 1 < nt) {
      GSTAGE(bi ^ 1, (t + 1) * 64);
      asm volatile("s_waitcnt vmcnt(6)" ::: "memory");
    } else {
      asm volatile("s_waitcnt vmcnt(0)" ::: "memory");
    }
    __builtin_amdgcn_s_barrier();
    asm volatile("" ::: "memory");

    const char* AB = (const char*)As + bi * 8192;
    const char* BB = (const char*)Bs + bi * 16384;
    bf16x8 af[2][2], bfr[4][2];
    #pragma unroll
    for (int mt = 0; mt < 2; ++mt) {
      int row = wr + mt * 16 + l15;
      #pragma unroll
      for (int c = 0; c < 2; ++c)
        af[mt][c] = *(const bf16x8*)(AB + row * 128 + (((c * 4 + g) ^ (row & 7)) << 4));
    }
    #pragma unroll
    for (int nt2 = 0; nt2 < 4; ++nt2) {
      int row = wc + nt2 * 16 + l15;
      #pragma unroll
      for (int c = 0; c < 2; ++c)
        bfr[nt2][c] = *(const bf16x8*)(BB + row * 128 + (((c * 4 + g) ^ (row & 7)) << 4));
    }
    #pragma unroll
    for (int c = 0; c < 2; ++c)
      #pragma unroll
      for (int mt = 0; mt < 2; ++mt)
        #pragma unroll
        for (int nt2 = 0; nt2 < 4; ++nt2)
          acc[mt][nt2] = __builtin_amdgcn_mfma_f32_16x16x32_bf16(af[mt][c], bfr[nt2][c], acc[mt][nt2], 0, 0, 0);

    asm volatile("" ::: "memory");
    __builtin_amdgcn_s_barrier();
    bi ^= 1;
  }
#undef GSTAGE

  if (blockIdx.y < 10) {
    const bool isq = (blockIdx.y < 8);
    const float qsc = isq ? 0.18033688f : 1.0f;   // 0.125*log2(e) folded into q
    #pragma unroll
    for (int mt = 0; mt < 2; ++mt)
      #pragma unroll
      for (int r4 = 0; r4 < 4; ++r4) {
        int m = m0 + wr + mt * 16 + 4 * g + r4;
        int s = m & (CS - 1), bb = m >> 11;
        #pragma unroll
        for (int nt2 = 0; nt2 < 4; ++nt2) {
          int n = n0 + wc + nt2 * 16 + l15;
          int d = n & 63;
          float val = acc[mt][nt2][r4];
          float par = __shfl_xor(val, 1, 64);
          float cv = fc[s * 32 + (d >> 1)];
          float sv = fs[s * 32 + (d >> 1)];
          float o = (d & 1) ? (par * sv + val * cv) : (val * cv - par * sv);
          o *= qsc;
          if (isq) {
            int h = n >> 6;
            ((unsigned short*)qb)[(((size_t)bb * CH + h) * CS + s) * CHD + d] = f2bf(o);
          } else {
            int kh = (n >> 6) - 16;
            ((unsigned short*)kb)[(((size_t)bb * CKH + kh) * CS + s) * CHD + d] = f2bf(o);
          }
        }
      }
  } else {
    #pragma unroll
    for (int mt = 0; mt < 2; ++mt) {
      int mb = m0 + wr + mt * 16 + 4 * g;
      int s0 = mb & (CS - 1), bb = mb >> 11;
      #pragma unroll
      for (int nt2 = 0; nt2 < 4; ++nt2) {
        int n = n0 + wc + nt2 * 16 + l15;
        int d = n & 63;
        int kh = (n >> 6) - 20;
        ushort4 pk = make_ushort4(f2bf(acc[mt][nt2][0]), f2bf(acc[mt][nt2][1]),
                                  f2bf(acc[mt][nt2][2]), f2bf(acc[mt][nt2][3]));
        *(ushort4*)&((unsigned short*)vt)[(((size_t)bb * CKH + kh) * CHD + d) * CS + s0] = pk;
      }
    }
  }
}

// ---------------------------------------------------------------------------
// Merged prep (R13-proven): conv_x (blocks 0..2047) + 4 weight transposes.
// ---------------------------------------------------------------------------
__global__ __launch_bounds__(256) void prep_kernel(
    const float* __restrict__ x, bf16* __restrict__ xb,
    const float* __restrict__ wq, const float* __restrict__ wk,
    const float* __restrict__ wv, const float* __restrict__ wo,
    bf16* __restrict__ wqkvt, bf16* __restrict__ wot)
{
  const int tid = threadIdx.x;
  int bid = blockIdx.x;
  if (bid < 2048) {
    int i = (bid * 256 + tid) * 8;
    float4 a = *(const float4*)&x[i];
    float4 b = *(const float4*)&x[i + 4];
    unsigned short* o = (unsigned short*)xb + i;
    *(ushort4*)o = make_ushort4(f2bf(a.x), f2bf(a.y), f2bf(a.z), f2bf(a.w));
    *(ushort4*)(o + 4) = make_ushort4(f2bf(b.x), f2bf(b.y), f2bf(b.z), f2bf(b.w));
    return;
  }
  bid -= 2048;
  const float* W; bf16* Wt; int Nn, bx, by;
  if (bid < 256)      { W = wq; Wt = wqkvt;                      Nn = 1024; bx = bid & 15;        by = bid >> 4; }
  else if (bid < 320) { W = wk; Wt = wqkvt + (size_t)1024 * CD;  Nn = 256;  bx = (bid-256) & 15;  by = (bid-256) >> 4; }
  else if (bid < 384) { W = wv; Wt = wqkvt + (size_t)1280 * CD;  Nn = 256;  bx = (bid-320) & 15;  by = (bid-320) >> 4; }
  else                { W = wo; Wt = wot;                        Nn = 1024; bx = (bid-384) & 15;  by = (bid-384) >> 4; }
  const int Kk = 1024;
  const int k0 = bx * 64;
  const int n0 = by * 64;

  __shared__ float T[64][65];
  const int lr = tid >> 4;
  const int lc = (tid & 15) * 4;
  #pragma unroll
  for (int i = 0; i < 4; ++i) {
    float4 v = *(const float4*)&W[(size_t)(k0 + lr + i * 16) * Nn + n0 + lc];
    T[lr + i * 16][lc + 0] = v.x;
    T[lr + i * 16][lc + 1] = v.y;
    T[lr + i * 16][lc + 2] = v.z;
    T[lr + i * 16][lc + 3] = v.w;
  }
  __syncthreads();
  const int rn = tid >> 3;
  const int ck = (tid & 7) * 8;
  #pragma unroll
  for (int i = 0; i < 2; ++i) {
    int nn = rn + i * 32;
    unsigned short u[8];
    #pragma unroll
    for (int e = 0; e < 8; ++e) u[e] = f2bf(T[ck + e][nn]);
    unsigned short* dst = (unsigned short*)Wt + (size_t)(n0 + nn) * Kk + k0 + ck;
    *(ushort4*)dst = make_ushort4(u[0], u[1], u[2], u[3]);
    *(ushort4*)(dst + 4) = make_ushort4(u[4], u[5], u[6], u[7]);
  }
}

// ---------------------------------------------------------------------------
// MFMA flash attention (R19 structure). R20 deltas (VALU-cut only):
// (a) truncation pair-pack via __builtin_amdgcn_perm (1 VALU vs 3-4,
//     bit-identical: sel 0x07060302 -> [pe1.b3,pe1.b2,pe0.b3,pe0.b2]);
// (b) running-max via max3-fusable triple trees (15 -> ~8 ops).
// ---------------------------------------------------------------------------
__global__ __launch_bounds__(256, 2) void flash_split_kernel(
    const bf16* __restrict__ qb, const bf16* __restrict__ kb,
    const bf16* __restrict__ vt, bf16* __restrict__ oc0,
    bf16* __restrict__ ob, float2* __restrict__ ml)
{
  __shared__ __align__(16) char arena[32768];
  char* KL = arena;                       // [2][8192]: K tile 64x(64 bf16)
  char* VL = arena + 16384;               // [2][8192]: V^T tile 64x(64 bf16)
  const int tid = threadIdx.x;
  const int lane = tid & 63;
  const int wid = tid >> 6;
  const int l15 = lane & 15;
  const int g = lane >> 4;
  const int blk = blockIdx.x;
  const int chunk = blk & 1;
  const int grp = (blk >> 1) & 7;         // b*4+kh
  const int idx = blk >> 4;               // 0..63
  const int qt = 63 - idx;                // longest pairs first
  const int kh = grp & 3;
  const int b = grp >> 2;
  const int h = kh * CREP + wid;
  const int N64 = (qt >> 1) + 1;
  const int hc = N64 >> 1;
  const int tbeg = chunk ? hc : 0;
  const int tend = chunk ? N64 : hc;

  const bf16* qbase = qb + ((size_t)(b * CH + h) * CS + qt * 32) * CHD;
  const bf16* kbase = kb + (size_t)(b * CKH + kh) * CS * CHD;
  const bf16* vbase = vt + (size_t)(b * CKH + kh) * CHD * CS;  // [d][s]

  bf16x8 qf[2][2];
  #pragma unroll
  for (int qs = 0; qs < 2; ++qs)
    #pragma unroll
    for (int c = 0; c < 2; ++c)
      qf[qs][c] = *(const bf16x8*)(qbase + (qs * 16 + l15) * CHD + c * 32 + g * 8);

  bf16x4 ones4;
  #pragma unroll
  for (int e = 0; e < 4; ++e) ones4[e] = (short)0x3F80;  // bf16 1.0

  f32x4 oacc[2][4];
  f32x4 lacc[2];
  #pragma unroll
  for (int qs = 0; qs < 2; ++qs) {
    lacc[qs] = (f32x4){0.f, 0.f, 0.f, 0.f};
    #pragma unroll
    for (int dt = 0; dt < 4; ++dt)
      oacc[qs][dt] = (f32x4){0.f, 0.f, 0.f, 0.f};
  }
  float mrow[2] = {-1e30f, -1e30f};

  const int slr = tid >> 3;
  const int scg = (tid & 7) ^ (slr & 7);
  const bf16* kstage = kbase + (size_t)slr * CHD + scg * 8;
  const bf16* vstage = vbase + (size_t)slr * CS + scg * 8;
  char* kdst = KL + wid * 1024;
  char* vdst = VL + wid * 1024;

#define STAGE(bi, t64) do {                                        \
    const bf16* ks_ = kstage + (size_t)(t64) * 64 * CHD;           \
    const bf16* vs_ = vstage + (t64) * 64;                         \
    gload_lds16(ks_,            kdst + (bi) * 8192);               \
    gload_lds16(ks_ + 32 * CHD, kdst + (bi) * 8192 + 4096);        \
    gload_lds16(vs_,            vdst + (bi) * 8192);               \
    gload_lds16(vs_ + 32 * CS,  vdst + (bi) * 8192 + 4096);        \
  } while (0)

  if (tbeg < tend) {
    int bi = 0;
    STAGE(0, tbeg);
    for (int t = tbeg; t < tend; ++t) {
      if (t + 1 < tend) {
        STAGE(bi ^ 1, t + 1);
        asm volatile("s_waitcnt vmcnt(4)" ::: "memory");
      } else {
        asm volatile("s_waitcnt vmcnt(0)" ::: "memory");
      }
      __builtin_amdgcn_s_barrier();
      asm volatile("" ::: "memory");

      const char* KB = KL + bi * 8192;
      const char* VB = VL + bi * 8192;
      bf16x8 kfr[4][2];
      #pragma unroll
      for (int kt = 0; kt < 4; ++kt) {
        int row = kt * 16 + l15;
        #pragma unroll
        for (int c = 0; c < 2; ++c)
          kfr[kt][c] = *(const bf16x8*)(KB + row * 128 + (((c * 4 + g) ^ (row & 7)) << 4));
      }
      // V fragments for K16 PV (R19-proven mapping)
      bf16x4 vfr16[4][4];
      #pragma unroll
      for (int dt = 0; dt < 4; ++dt) {
        int row = dt * 16 + l15;
        #pragma unroll
        for (int kt = 0; kt < 4; ++kt)
          vfr16[dt][kt] = *(const bf16x4*)(VB + row * 128 +
              (((2 * kt + (g >> 1)) ^ (row & 7)) << 4) + (g & 1) * 8);
      }

      // QK^T (swapped): S^T[k][q] — exp2 domain (Q pre-scaled)
      f32x4 sacc[4][2];
      #pragma unroll
      for (int kt = 0; kt < 4; ++kt)
        #pragma unroll
        for (int qs = 0; qs < 2; ++qs)
          sacc[kt][qs] = (f32x4){0.f, 0.f, 0.f, 0.f};
      #pragma unroll
      for (int c = 0; c < 2; ++c)
        #pragma unroll
        for (int kt = 0; kt < 4; ++kt)
          #pragma unroll
          for (int qs = 0; qs < 2; ++qs)
            sacc[kt][qs] = __builtin_amdgcn_mfma_f32_16x16x32_bf16(kfr[kt][c], qf[qs][c], sacc[kt][qs], 0, 0, 0);

      const bool diag = (t == N64 - 1);   // only reachable in chunk1
      #pragma unroll
      for (int qs = 0; qs < 2; ++qs) {
        float pe[16];
        #pragma unroll
        for (int kt = 0; kt < 4; ++kt)
          #pragma unroll
          for (int r = 0; r < 4; ++r) {
            float v = sacc[kt][qs][r];
            if (diag) {
              int koff = t * 64 + kt * 16 + 4 * g + r;
              if (koff > qt * 32 + qs * 16 + l15) v = -1e30f;
            }
            pe[kt * 4 + r] = v;
          }
        // max via v_max3-fusable triples: 15 fmax -> 5 max3 + 2 max3 + 1 fmax
        float t0 = fmaxf(fmaxf(pe[0], pe[1]), pe[2]);
        float t1 = fmaxf(fmaxf(pe[3], pe[4]), pe[5]);
        float t2 = fmaxf(fmaxf(pe[6], pe[7]), pe[8]);
        float t3 = fmaxf(fmaxf(pe[9], pe[10]), pe[11]);
        float t4 = fmaxf(fmaxf(pe[12], pe[13]), pe[14]);
        float pm = fmaxf(fmaxf(fmaxf(t0, t1), t2), fmaxf(fmaxf(t3, t4), pe[15]));
        if (__any(pm > mrow[qs] + 8.0f)) {       // slow path: exact rescale
          pm = fmaxf(pm, __shfl_xor(pm, 16, 64));
          pm = fmaxf(pm, __shfl_xor(pm, 32, 64));
          float nm = fmaxf(mrow[qs], pm);
          float corr = exp2f(mrow[qs] - nm);
          mrow[qs] = nm;
          lacc[qs] *= corr;
          #pragma unroll
          for (int dt = 0; dt < 4; ++dt) oacc[qs][dt] *= corr;
        }
        #pragma unroll
        for (int i = 0; i < 16; ++i)
          pe[i] = exp2f(pe[i] - mrow[qs]);       // p <= 2^8
        // truncation pair-pack via v_perm_b32 (bit-identical to and/shift/or)
        #pragma unroll
        for (int kt = 0; kt < 4; ++kt) {
          union { uint2 u; bf16x4 v; } cv;
          cv.u.x = __builtin_amdgcn_perm(__float_as_uint(pe[kt * 4 + 1]),
                                         __float_as_uint(pe[kt * 4 + 0]),
                                         0x07060302u);
          cv.u.y = __builtin_amdgcn_perm(__float_as_uint(pe[kt * 4 + 3]),
                                         __float_as_uint(pe[kt * 4 + 2]),
                                         0x07060302u);
          // PV + psum for this kt, straight from registers (R19-proven)
          lacc[qs] = mfma16bf16(ones4, cv.v, lacc[qs]);
          #pragma unroll
          for (int dt = 0; dt < 4; ++dt)
            oacc[qs][dt] = mfma16bf16(vfr16[dt][kt], cv.v, oacc[qs][dt]);
        }
      }

      asm volatile("" ::: "memory");
      __builtin_amdgcn_s_barrier();
      bi ^= 1;
    }
  }
#undef STAGE

  // partial write: unnormalized O (bf16) + (m,l). Kernel boundary = sync.
  unsigned short* pdst = (unsigned short*)(chunk ? ob : oc0);
  #pragma unroll
  for (int qs = 0; qs < 2; ++qs) {
    int qg = qt * 32 + qs * 16 + l15;
    unsigned short* prow = pdst + (size_t)(b * CS + qg) * CNQ + h * CHD;
    #pragma unroll
    for (int dt = 0; dt < 4; ++dt)
      *(ushort4*)&prow[dt * 16 + 4 * g] =
          make_ushort4(f2bf(oacc[qs][dt][0]), f2bf(oacc[qs][dt][1]),
                       f2bf(oacc[qs][dt][2]), f2bf(oacc[qs][dt][3]));
    if (g == 0)
      ml[(((size_t)chunk * CB + b) * CH + h) * CS + qg] = make_float2(mrow[qs], lacc[qs][0]);
  }
}

// ---------------------------------------------------------------------------
// Merge: final_o = (c0*o0 + c1*o1) / (c0*l0 + c1*l1), in-place over ob.
// ---------------------------------------------------------------------------
__global__ __launch_bounds__(256) void merge_kernel(
    const bf16* __restrict__ oc0, bf16* __restrict__ ob,
    const float2* __restrict__ ml)
{
  const int e8 = blockIdx.x * 256 + threadIdx.x;     // 0 .. 524287
  const size_t off = (size_t)e8 * 8;
  const int row = (int)(off >> 10);                  // b*CS + s
  const int col = (int)(off & 1023);
  const int h = col >> 6;
  const int b = row >> 11;
  const int s = row & (CS - 1);
  float2 ml0 = ml[(((size_t)0 * CB + b) * CH + h) * CS + s];
  float2 ml1 = ml[(((size_t)1 * CB + b) * CH + h) * CS + s];
  float M = fmaxf(ml0.x, ml1.x);
  float c0 = exp2f(ml0.x - M), c1 = exp2f(ml1.x - M);
  float inv = 1.0f / (c0 * ml0.y + c1 * ml1.y);
  ushort4 a0 = *(const ushort4*)((const unsigned short*)oc0 + off);
  ushort4 a1 = *(const ushort4*)((const unsigned short*)oc0 + off + 4);
  ushort4 b0 = *(const ushort4*)((const unsigned short*)ob + off);
  ushort4 b1 = *(const ushort4*)((const unsigned short*)ob + off + 4);
  unsigned short r[8];
  const unsigned short* p0 = &a0.x;
  const unsigned short* p1 = &b0.x;
  #pragma unroll
  for (int i = 0; i < 4; ++i)
    r[i] = f2bf((c0 * bf2f(p0[i]) + c1 * bf2f(p1[i])) * inv);
  p0 = &a1.x; p1 = &b1.x;
  #pragma unroll
  for (int i = 0; i < 4; ++i)
    r[4 + i] = f2bf((c0 * bf2f(p0[i]) + c1 * bf2f(p1[i])) * inv);
  *(ushort4*)((unsigned short*)ob + off) = make_ushort4(r[0], r[1], r[2], r[3]);
  *(ushort4*)((unsigned short*)ob + off + 4) = make_ushort4(r[4], r[5], r[6], r[7]);
}

// ---------------------------------------------------------------------------
extern "C" void kernel_launch(void* const* d_in, const int* in_sizes, int n_in,
                              void* d_out, int out_size, void* d_ws, size_t ws_size,
                              hipStream_t stream)
{
  const float* x  = (const float*)d_in[0];
  const float* wq = (const float*)d_in[1];
  const float* wk = (const float*)d_in[2];
  const float* wv = (const float*)d_in[3];
  const float* wo = (const float*)d_in[4];
  const float* fc = (const float*)d_in[5];
  const float* fs = (const float*)d_in[6];
  float* out = (float*)d_out;

  char* ws = (char*)d_ws;
  // workspace (peak ~34.6MB):
  bf16*   x_b   = (bf16*)(ws);
  bf16*   wqkvt = (bf16*)(ws + 8388608);
  bf16*   wot   = (bf16*)(ws + 11534336);
  bf16*   q_b   = (bf16*)(ws + 13631488);
  bf16*   k_b   = (bf16*)(ws + 22020096);
  bf16*   v_t   = (bf16*)(ws + 24117248);
  bf16*   o_b   = (bf16*)(ws);               // over x_b
  bf16*   oc0   = (bf16*)(ws + 26214400);
  float2* mlb   = (float2*)(ws + 34603008);

  prep_kernel<<<2688, 256, 0, stream>>>(x, x_b, wq, wk, wv, wo, wqkvt, wot);
  gemm_qkv_rope_kernel<<<dim3(64, 12), 256, 0, stream>>>(x_b, wqkvt, fc, fs, q_b, k_b, v_t);
  flash_split_kernel<<<1024, 256, 0, stream>>>(q_b, k_b, v_t, oc0, o_b, mlb);
  merge_kernel<<<2048, 256, 0, stream>>>(oc0, o_b, mlb);
  gemm_mfma_kernel<<<dim3(64, 8), 256, 0, stream>>>(o_b, wot, out, CM, CD, CNQ, CNQ);
}